// Round 1
// 1183.436 us; speedup vs baseline: 1.2310x; 1.2310x over previous
//
#include <hip/hip_runtime.h>
#include <math.h>

// Problem constants (idx == 10 branch; shapes fixed by setup_inputs)
#define L_    3136          // 56*56
#define R_    25088         // 8*L
#define C_    256
#define MATF  6422528       // 256 * R_

typedef __attribute__((ext_vector_type(8))) short s16x8;
typedef __attribute__((ext_vector_type(4))) float f32x4;
typedef unsigned short us;

// ---------- bf16 split helpers ----------
__device__ __forceinline__ us bfh(float v) {
    unsigned u = __float_as_uint(v);
    u = (u + 0x7FFFu + ((u >> 16) & 1u)) >> 16;   // RNE
    return (us)u;
}
__device__ __forceinline__ float bf2f(us h) { return __uint_as_float((unsigned)h << 16); }
__device__ __forceinline__ void split2(float v, us& h, us& l) {
    h = bfh(v);
    l = bfh(v - bf2f(h));
}
__device__ __forceinline__ uint4 packu4(const us* s) {
    uint4 u;
    u.x = (unsigned)s[0] | ((unsigned)s[1] << 16);
    u.y = (unsigned)s[2] | ((unsigned)s[3] << 16);
    u.z = (unsigned)s[4] | ((unsigned)s[5] << 16);
    u.w = (unsigned)s[6] | ((unsigned)s[7] << 16);
    return u;
}
__device__ __forceinline__ uint2 packu2(const us* s) {
    uint2 u;
    u.x = (unsigned)s[0] | ((unsigned)s[1] << 16);
    u.y = (unsigned)s[2] | ((unsigned)s[3] << 16);
    return u;
}

// async global->LDS 16B (wave-uniform base + lane*16 dest; integer detour for AS casts)
__device__ __forceinline__ void gl16(const us* g, const us* l) {
    __builtin_amdgcn_global_load_lds(
        (const __attribute__((address_space(1))) unsigned int*)(unsigned long long)(const void*)g,
        (__attribute__((address_space(3))) unsigned int*)(unsigned int)(unsigned long long)(const void*)l,
        16, 0, 0);
}

// ---------- weight convert: fp32 [M][K] -> swizzled bf16 hi/lo [M][K] ----------
__device__ __forceinline__ void wconv_body(const float* __restrict__ src,
        us* __restrict__ dh, us* __restrict__ dl, int idx, int kgs, int K)
{
    int m  = idx >> kgs;
    int gk = idx & ((1 << kgs) - 1);
    const float* sp = src + (size_t)m * K + gk * 8;
    float4 v0 = *(const float4*)sp;
    float4 v1 = *(const float4*)(sp + 4);
    float vv[8] = {v0.x, v0.y, v0.z, v0.w, v1.x, v1.y, v1.z, v1.w};
    us hh[8], ll[8];
    #pragma unroll
    for (int e = 0; e < 8; e++) split2(vv[e], hh[e], ll[e]);
    int p = gk ^ ((m >> 1) & 7);           // 3-bit XOR swizzle within aligned 8-granule groups
    size_t off = (size_t)m * K + (size_t)p * 8;
    *(uint4*)(dh + off) = packu4(hh);
    *(uint4*)(dl + off) = packu4(ll);
}

__global__ __launch_bounds__(256)
void wconv1_k(const float* __restrict__ w, us* __restrict__ dh, us* __restrict__ dl)
{   // conv_w: M=256 K=512 -> 16384 granules -> 64 blocks
    wconv_body(w, dh, dl, blockIdx.x * 256 + threadIdx.x, 6, 512);
}

__global__ __launch_bounds__(256)
void wconv6_k(const float* __restrict__ q, const float* __restrict__ k,
              const float* __restrict__ v, const float* __restrict__ o,
              const float* __restrict__ l1, const float* __restrict__ l2,
              us* __restrict__ wb)
{
    int bid = blockIdx.x;
    const float* src; us* dh; us* dl; int kgs, K;
    if (bid < 32)       { src = q;  dh = wb;           dl = wb + 65536;   kgs = 5; K = 256;  }
    else if (bid < 64)  { src = k;  dh = wb + 131072;  dl = wb + 196608;  kgs = 5; K = 256;  bid -= 32;  }
    else if (bid < 96)  { src = v;  dh = wb + 262144;  dl = wb + 327680;  kgs = 5; K = 256;  bid -= 64;  }
    else if (bid < 128) { src = o;  dh = wb + 393216;  dl = wb + 458752;  kgs = 5; K = 256;  bid -= 96;  }
    else if (bid < 256) { src = l1; dh = wb + 524288;  dl = wb + 786432;  kgs = 5; K = 256;  bid -= 128; }
    else                { src = l2; dh = wb + 1048576; dl = wb + 1310720; kgs = 7; K = 1024; bid -= 256; }
    wconv_body(src, dh, dl, bid * 256 + threadIdx.x, kgs, K);
}

// ---------- transpose-convert: fp32 [nb][C][Lb] -> swizzled bf16 hi/lo [nb*Lb][C] ----------
__global__ __launch_bounds__(256)
void tconv_k(const float* __restrict__ src, us* __restrict__ dh, us* __restrict__ dl,
             int C, int Lb)
{
    __shared__ float tl[64][68];
    int l0 = blockIdx.x * 64, c0 = blockIdx.y * 64, b = blockIdx.z;
    int t = threadIdx.x;
    {
        int cl = t >> 2, qq = t & 3;
        const float* sp = src + ((size_t)b * C + c0 + cl) * Lb + l0 + qq * 16;
        #pragma unroll
        for (int i = 0; i < 4; i++) {
            float4 v = *(const float4*)(sp + i * 4);
            *(float4*)&tl[cl][qq * 16 + i * 4] = v;
        }
    }
    __syncthreads();
    int rl = t & 63, cq = t >> 6;          // lanes over rows: conflict-free LDS column reads
    size_t r = (size_t)b * Lb + l0 + rl;
    int s3 = ((l0 + rl) >> 1) & 7;
    size_t rowo = r * (size_t)C;
    #pragma unroll
    for (int half = 0; half < 2; half++) {
        us hh[8], ll[8];
        #pragma unroll
        for (int e = 0; e < 8; e++)
            split2(tl[cq * 16 + half * 8 + e][rl], hh[e], ll[e]);
        int gfull = (c0 >> 3) + cq * 2 + half;
        int p = gfull ^ s3;
        *(uint4*)(dh + rowo + (size_t)p * 8) = packu4(hh);
        *(uint4*)(dl + rowo + (size_t)p * 8) = packu4(ll);
    }
}

// ---------- MFMA split-bf16 GEMM: C[m][r] = W[m][:] . Xt[r][:] ----------
#define GBM 128
#define GBN 64
#define GBK 64
enum { GE_F32 = 0, GE_CONVT = 1, GE_GELUT = 2 };

template<int EPI>
__global__ __launch_bounds__(256)
void gemm_mf(const us* __restrict__ Wh, const us* __restrict__ Wl,
             const us* __restrict__ Xh, const us* __restrict__ Xl,
             float* __restrict__ Yf, us* __restrict__ Yth, us* __restrict__ Ytl,
             const float* __restrict__ bias, const float* __restrict__ bnw,
             const float* __restrict__ bnb, const float* __restrict__ pos,
             int K, int mts, int Mrow)
{
    __shared__ us Ah[GBM * GBK];
    __shared__ us Al[GBM * GBK];
    __shared__ us Bh[GBN * GBK];
    __shared__ us Bl[GBN * GBK];

    const int tid = threadIdx.x;
    // XCD-bijective remap (nwg % 8 == 0 for all launches), m-fastest for B-panel L2 reuse
    int nwg = gridDim.x;
    int wg = (blockIdx.x & 7) * (nwg >> 3) + (blockIdx.x >> 3);
    int mt = wg & ((1 << mts) - 1);
    int rt = wg >> mts;
    const int m0 = mt * GBM;
    const int r0 = rt * GBN;

    const us* Ahg = Wh + (size_t)m0 * K;
    const us* Alg = Wl + (size_t)m0 * K;
    const us* Bhg = Xh + (size_t)r0 * K;
    const us* Blg = Xl + (size_t)r0 * K;

    const int lane = tid & 63;
    const int w    = tid >> 6;
    const int wm   = (w >> 1) * 64;
    const int wr   = (w & 1) * 32;
    const int l15  = lane & 15;
    const int lg   = lane >> 4;

    f32x4 acc[4][2];
    #pragma unroll
    for (int a = 0; a < 4; a++)
        #pragma unroll
        for (int b = 0; b < 2; b++)
            acc[a][b] = (f32x4){0.f, 0.f, 0.f, 0.f};

    for (int k0 = 0; k0 < K; k0 += GBK) {
        // stage A (128x64x2B x2 planes) + B (64x64x2B x2 planes), linear LDS dest
        #pragma unroll
        for (int q = 0; q < 4; q++) {
            int g = q * 256 + tid;
            int row = g >> 3, sub = (g & 7) << 3;
            gl16(Ahg + (size_t)row * K + k0 + sub, Ah + g * 8);
            gl16(Alg + (size_t)row * K + k0 + sub, Al + g * 8);
        }
        #pragma unroll
        for (int q = 0; q < 2; q++) {
            int g = q * 256 + tid;
            int row = g >> 3, sub = (g & 7) << 3;
            gl16(Bhg + (size_t)row * K + k0 + sub, Bh + g * 8);
            gl16(Blg + (size_t)row * K + k0 + sub, Bl + g * 8);
        }
        __syncthreads();
        #pragma unroll
        for (int kk = 0; kk < 2; kk++) {
            s16x8 ah[4], al[4], bh[2], bl[2];
            #pragma unroll
            for (int a = 0; a < 4; a++) {
                int row = wm + a * 16 + l15;
                int p = ((kk << 2) | lg) ^ ((row >> 1) & 7);
                ah[a] = *(const s16x8*)(Ah + row * GBK + p * 8);
                al[a] = *(const s16x8*)(Al + row * GBK + p * 8);
            }
            #pragma unroll
            for (int b = 0; b < 2; b++) {
                int row = wr + b * 16 + l15;
                int p = ((kk << 2) | lg) ^ ((row >> 1) & 7);
                bh[b] = *(const s16x8*)(Bh + row * GBK + p * 8);
                bl[b] = *(const s16x8*)(Bl + row * GBK + p * 8);
            }
            #pragma unroll
            for (int a = 0; a < 4; a++)
                #pragma unroll
                for (int b = 0; b < 2; b++) {
                    acc[a][b] = __builtin_amdgcn_mfma_f32_16x16x32_bf16(ah[a], bh[b], acc[a][b], 0, 0, 0);
                    acc[a][b] = __builtin_amdgcn_mfma_f32_16x16x32_bf16(ah[a], bl[b], acc[a][b], 0, 0, 0);
                    acc[a][b] = __builtin_amdgcn_mfma_f32_16x16x32_bf16(al[a], bh[b], acc[a][b], 0, 0, 0);
                }
        }
        __syncthreads();
    }

    // epilogue: D row=(lane>>4)*4+reg (m-dim), col=lane&15 (r-dim)
    if (EPI == GE_F32) {
        #pragma unroll
        for (int a = 0; a < 4; a++) {
            int mb = m0 + wm + a * 16 + lg * 4;
            #pragma unroll
            for (int b = 0; b < 2; b++) {
                int rr = r0 + wr + b * 16 + l15;
                #pragma unroll
                for (int q = 0; q < 4; q++)
                    Yf[(size_t)(mb + q) * R_ + rr] = acc[a][b][q] + bias[mb + q];
            }
        }
    } else {
        #pragma unroll
        for (int b = 0; b < 2; b++) {
            int rr = r0 + wr + b * 16 + l15;
            int s3 = (rr >> 1) & 7;
            int l = rr % L_;
            size_t rowo = (size_t)rr * Mrow;
            #pragma unroll
            for (int a = 0; a < 4; a++) {
                int mb = m0 + wm + a * 16 + lg * 4;
                us hh[4], ll[4];
                #pragma unroll
                for (int q = 0; q < 4; q++) {
                    int m = mb + q;
                    float v = acc[a][b][q] + bias[m];
                    if (EPI == GE_CONVT) {
                        v = v * 0.9999950000374997f * bnw[m] + bnb[m];
                        v += pos[(size_t)m * L_ + l];
                    } else {
                        v = 0.5f * v * (1.f + erff(v * 0.7071067811865475f));
                    }
                    split2(v, hh[q], ll[q]);
                }
                int p = (mb >> 3) ^ s3;
                size_t off = rowo + (size_t)((p << 3) | (mb & 7));
                *(uint2*)(Yth + off) = packu2(hh);
                *(uint2*)(Ytl + off) = packu2(ll);
            }
        }
    }
}

// pos[c][l]: c<64: sin(y*om) | <128: cos(y*om) | <192: sin(x*om) | <256: cos(x*om)
__global__ __launch_bounds__(256)
void pos_k(float* __restrict__ pos)
{
    int c = blockIdx.x;
    int q = c >> 6, t = c & 63;
    float om = exp2f(-(float)t * (13.287712379549449f / 64.f));  // 10000^(-t/64)
    for (int l = threadIdx.x; l < L_; l += 256) {
        int y = l / 56, x = l - y * 56;
        float arg = (q < 2 ? (float)y : (float)x) * om;
        pos[(size_t)c * L_ + l] = (q & 1) ? cosf(arg) : sinf(arg);
    }
}

// avgpool2(a3) -> a3d (fp32 residual) and xq_t = bf16T(a3d + pos) (swizzled)
__global__ __launch_bounds__(256)
void pool_k(const float* __restrict__ a3, const float* __restrict__ pos,
            float* __restrict__ a3d, us* __restrict__ xh, us* __restrict__ xl)
{
    __shared__ us hi[256][34];
    __shared__ us lo[256][34];
    int blk = blockIdx.x;                 // 784 = 8b * 98 lblk
    int b = blk / 98, l0 = (blk % 98) * 32;
    int t = threadIdx.x;
    {
        int lt = t & 31, cg = t >> 5;
        int l = l0 + lt;
        int y = l / 56, x = l - y * 56;
        const float* srow = a3 + ((size_t)b * 256) * 12544 + (2 * y) * 112 + 2 * x;
        float* drow = a3d + (size_t)b * L_ + l;
        const float* prow = pos + l;
        for (int cc = 0; cc < 32; cc++) {
            int c = cc * 8 + cg;
            const float* sp = srow + (size_t)c * 12544;
            float2 v0 = *(const float2*)sp;
            float2 v1 = *(const float2*)(sp + 112);
            float v = (v0.x + v0.y + v1.x + v1.y) * 0.25f;
            drow[(size_t)c * R_] = v;
            split2(v + prow[(size_t)c * L_], hi[c][lt], lo[c][lt]);
        }
    }
    __syncthreads();
    int j = t & 31, cq = t >> 5;
    int r = b * L_ + l0 + j;
    int s3 = ((l0 + j) >> 1) & 7;
    size_t rowo = (size_t)r * 256;
    #pragma unroll
    for (int gg = 0; gg < 4; gg++) {
        int cb = cq * 32 + gg * 8;
        us hh[8], ll[8];
        #pragma unroll
        for (int e = 0; e < 8; e++) { hh[e] = hi[cb + e][j]; ll[e] = lo[cb + e][j]; }
        int p = ((cq << 2) | gg) ^ s3;
        *(uint4*)(xh + rowo + (size_t)p * 8) = packu4(hh);
        *(uint4*)(xl + rowo + (size_t)p * 8) = packu4(ll);
    }
}

// In-place LayerNorm (eps 1e-5) over channel dim then l2-normalize (max(n,1e-4)).
__global__ __launch_bounds__(256)
void ln_l2_k(float* __restrict__ X, const float* __restrict__ wt, const float* __restrict__ bt)
{
    __shared__ float red[4][64];
    __shared__ float red2[4][64];
    int tid = threadIdx.x;
    int rr = tid & 63, og = tid >> 6;
    size_t r = (size_t)blockIdx.x * 64 + rr;
    float s1 = 0.f, s2 = 0.f;
    for (int j = 0; j < 64; j++) {
        float v = X[(size_t)(og * 64 + j) * R_ + r];
        s1 += v; s2 = fmaf(v, v, s2);
    }
    red[og][rr] = s1; red2[og][rr] = s2;
    __syncthreads();
    float mu  = (red[0][rr] + red[1][rr] + red[2][rr] + red[3][rr]) * (1.f / 256.f);
    float var = (red2[0][rr] + red2[1][rr] + red2[2][rr] + red2[3][rr]) * (1.f / 256.f) - mu * mu;
    float rstd = rsqrtf(var + 1e-5f);
    __syncthreads();
    float t2 = 0.f;
    for (int j = 0; j < 64; j++) {
        int o = og * 64 + j;
        float v = X[(size_t)o * R_ + r];
        float y = (v - mu) * rstd * wt[o] + bt[o];
        t2 = fmaf(y, y, t2);
    }
    red[og][rr] = t2;
    __syncthreads();
    float nrm = sqrtf(red[0][rr] + red[1][rr] + red[2][rr] + red[3][rr]);
    float scale = 1.f / fmaxf(nrm, 1e-4f);
    for (int j = 0; j < 64; j++) {
        int o = og * 64 + j;
        size_t ix = (size_t)o * R_ + r;
        float v = X[ix];
        X[ix] = (v - mu) * rstd * wt[o] * scale + bt[o] * scale;
    }
}

// In-place X = res + LayerNorm(X); optionally also bf16T swizzled copy for next GEMM
template<int TOUT>
__global__ __launch_bounds__(256)
void ln_res_k(float* __restrict__ X, const float* __restrict__ res,
              const float* __restrict__ wt, const float* __restrict__ bt,
              us* __restrict__ th, us* __restrict__ tl_)
{
    __shared__ float red[4][64];
    __shared__ float red2[4][64];
    int tid = threadIdx.x;
    int rr = tid & 63, og = tid >> 6;
    size_t r = (size_t)blockIdx.x * 64 + rr;
    float s1 = 0.f, s2 = 0.f;
    for (int j = 0; j < 64; j++) {
        float v = X[(size_t)(og * 64 + j) * R_ + r];
        s1 += v; s2 = fmaf(v, v, s2);
    }
    red[og][rr] = s1; red2[og][rr] = s2;
    __syncthreads();
    float mu  = (red[0][rr] + red[1][rr] + red[2][rr] + red[3][rr]) * (1.f / 256.f);
    float var = (red2[0][rr] + red2[1][rr] + red2[2][rr] + red2[3][rr]) * (1.f / 256.f) - mu * mu;
    float rstd = rsqrtf(var + 1e-5f);
    float yv[64];
    #pragma unroll
    for (int j = 0; j < 64; j++) {
        int o = og * 64 + j;
        size_t ix = (size_t)o * R_ + r;
        float v = X[ix];
        float y = res[ix] + (v - mu) * rstd * wt[o] + bt[o];
        X[ix] = y;
        yv[j] = y;
    }
    if (TOUT) {
        int s3 = ((int)r >> 1) & 7;
        size_t rowo = r * 256;
        #pragma unroll
        for (int g = 0; g < 8; g++) {
            us hh[8], ll[8];
            #pragma unroll
            for (int e = 0; e < 8; e++) split2(yv[g * 8 + e], hh[e], ll[e]);
            int p = ((og << 3) | g) ^ s3;
            *(uint4*)(th  + rowo + (size_t)p * 8) = packu4(hh);
            *(uint4*)(tl_ + rowo + (size_t)p * 8) = packu4(ll);
        }
    }
}

// Partial KV: kvp[n][slab][d][m] = sum_{l in slab} (d<32?cw:sw)[l]*K[l][d&31]*V[l][m]
__global__ __launch_bounds__(256)
void kv_part_k(const float* __restrict__ Kt, const float* __restrict__ Vt,
               float* __restrict__ kvp)
{
    __shared__ float kl[64][33];
    __shared__ float vl[64][33];
    __shared__ float cwl[64], swl[64];
    int slab = blockIdx.x;
    int n = blockIdx.y;
    int b = n >> 3, h = n & 7;
    int tid = threadIdx.x;
    int lane = tid & 63, grp = tid >> 6;
    int d = tid >> 2;
    int m0 = (tid & 3) * 8;
    float acc[8] = {0,0,0,0,0,0,0,0};
    size_t base = (size_t)(h * 32) * R_ + (size_t)b * L_;
    for (int ch = 0; ch < 7; ch++) {
        int l0 = slab * 448 + ch * 64;
        #pragma unroll
        for (int j = 0; j < 8; j++) {
            int dd = grp * 8 + j;
            kl[lane][dd] = Kt[base + (size_t)dd * R_ + l0 + lane];
            vl[lane][dd] = Vt[base + (size_t)dd * R_ + l0 + lane];
        }
        if (tid < 64) {
            float wi = (float)(l0 + tid + 1) * (1.f / 3136.f);
            cwl[tid] = cosf(wi); swl[tid] = sinf(wi);
        }
        __syncthreads();
        for (int l = 0; l < 64; l++) {
            float kvv = (d < 32 ? cwl[l] : swl[l]) * kl[l][d & 31];
            #pragma unroll
            for (int j = 0; j < 8; j++)
                acc[j] = fmaf(kvv, vl[l][m0 + j], acc[j]);
        }
        __syncthreads();
    }
    float* out = kvp + ((size_t)(n * 7 + slab)) * 2048 + d * 32 + m0;
    #pragma unroll
    for (int j = 0; j < 8; j++) out[j] = acc[j];
}

__global__ __launch_bounds__(256)
void kv_red_k(const float* __restrict__ kvp, float* __restrict__ kv)
{
    int idx = blockIdx.x * 256 + threadIdx.x;
    int n = idx >> 11, dm = idx & 2047;
    float s = 0.f;
    #pragma unroll
    for (int t = 0; t < 7; t++) s += kvp[((size_t)(n * 7 + t)) * 2048 + dm];
    kv[idx] = s;
}

// attn -> rmsnorm -> bf16T swizzled output [r][c=h*32+m]
__global__ __launch_bounds__(256)
void attn_k(const float* __restrict__ Q, const float* __restrict__ kv,
            const float* __restrict__ rmsw, us* __restrict__ Gh, us* __restrict__ Gl)
{
    __shared__ float kvl[2048];
    int h = blockIdx.y, b = blockIdx.z;
    int tid = threadIdx.x;
    int n = b * 8 + h;
    for (int i = tid; i < 2048; i += 256) kvl[i] = kv[(size_t)n * 2048 + i];
    __syncthreads();
    int l = blockIdx.x * 256 + tid;
    if (l >= L_) return;
    size_t r = (size_t)b * L_ + l;
    float qd[32];
    #pragma unroll
    for (int dd = 0; dd < 32; dd++) qd[dd] = Q[((size_t)(h * 32 + dd)) * R_ + r];
    float wi = (float)(l + 1) * (1.f / 3136.f);
    float cw = cosf(wi), sw = sinf(wi);
    float val[32]; float ss = 0.f;
    #pragma unroll
    for (int m = 0; m < 32; m++) {
        float s1 = 0.f, s2 = 0.f;
        #pragma unroll
        for (int dd = 0; dd < 32; dd++) {
            s1 = fmaf(qd[dd], kvl[dd * 32 + m], s1);
            s2 = fmaf(qd[dd], kvl[(dd + 32) * 32 + m], s2);
        }
        float v = cw * s1 + sw * s2;
        val[m] = v; ss = fmaf(v, v, ss);
    }
    float rinv = rsqrtf(ss * (1.f / 32.f) + 1e-6f);
    int s3 = (l >> 1) & 7;
    size_t rowo = r * 256;
    #pragma unroll
    for (int j = 0; j < 4; j++) {
        us hh[8], ll[8];
        #pragma unroll
        for (int e = 0; e < 8; e++) {
            float y = rmsw[j * 8 + e] * val[j * 8 + e] * rinv;
            split2(y, hh[e], ll[e]);
        }
        int p = ((h << 2) | j) ^ s3;
        *(uint4*)(Gh + rowo + (size_t)p * 8) = packu4(hh);
        *(uint4*)(Gl + rowo + (size_t)p * 8) = packu4(ll);
    }
}

__device__ __forceinline__ void bil_coord(int o, int lim, int& i0, int& i1, float& t)
{
    float f = o * 0.5f - 0.25f;
    float fl = floorf(f);
    t = f - fl;
    int i = (int)fl;
    i0 = i < 0 ? 0 : (i > lim ? lim : i);
    int ip = i + 1;
    i1 = ip < 0 ? 0 : (ip > lim ? lim : ip);
}

__global__ __launch_bounds__(256)
void up_a3_k(const float* __restrict__ out2, const float* __restrict__ a3,
             float* __restrict__ out)
{
    unsigned idx = blockIdx.x * 256u + threadIdx.x;
    int xo = idx % 112;
    unsigned t1 = idx / 112;
    int yo = t1 % 112;
    unsigned t2 = t1 / 112;
    int c = t2 & 255;
    int b = t2 >> 8;
    int x0, x1, y0, y1; float tx, ty;
    bil_coord(xo, 55, x0, x1, tx);
    bil_coord(yo, 55, y0, y1, ty);
    const float* src = out2 + (size_t)c * R_ + (size_t)b * L_;
    float v00 = src[y0 * 56 + x0], v01 = src[y0 * 56 + x1];
    float v10 = src[y1 * 56 + x0], v11 = src[y1 * 56 + x1];
    float v = (1.f - ty) * ((1.f - tx) * v00 + tx * v01) + ty * ((1.f - tx) * v10 + tx * v11);
    out[idx] = v * a3[idx];
}

__global__ __launch_bounds__(256)
void up_a4_k(const float* __restrict__ a4, float* __restrict__ out)
{
    unsigned idx = blockIdx.x * 256u + threadIdx.x;
    int xo = idx % 112;
    unsigned t1 = idx / 112;
    int yo = t1 % 112;
    unsigned t2 = t1 / 112;
    int c = t2 & 511;
    int b = t2 >> 9;
    int x0, x1, y0, y1; float tx, ty;
    bil_coord(xo, 55, x0, x1, tx);
    bil_coord(yo, 55, y0, y1, ty);
    const float* src = a4 + (size_t)(b * 512 + c) * 3136;
    float v00 = src[y0 * 56 + x0], v01 = src[y0 * 56 + x1];
    float v10 = src[y1 * 56 + x0], v11 = src[y1 * 56 + x1];
    out[idx] = (1.f - ty) * ((1.f - tx) * v00 + tx * v01) + ty * ((1.f - tx) * v10 + tx * v11);
}

extern "C" void kernel_launch(void* const* d_in, const int* in_sizes, int n_in,
                              void* d_out, int out_size, void* d_ws, size_t ws_size,
                              hipStream_t stream)
{
    const float* a3     = (const float*)d_in[0];
    const float* a4     = (const float*)d_in[1];
    const float* conv_w = (const float*)d_in[2];
    const float* conv_b = (const float*)d_in[3];
    const float* bn_w   = (const float*)d_in[4];
    const float* bn_b   = (const float*)d_in[5];
    const float* q_w    = (const float*)d_in[6];
    const float* q_b    = (const float*)d_in[7];
    const float* q_ln_w = (const float*)d_in[8];
    const float* q_ln_b = (const float*)d_in[9];
    const float* k_w    = (const float*)d_in[10];
    const float* k_b    = (const float*)d_in[11];
    const float* k_ln_w = (const float*)d_in[12];
    const float* k_ln_b = (const float*)d_in[13];
    const float* v_w    = (const float*)d_in[14];
    const float* v_b    = (const float*)d_in[15];
    const float* o_w    = (const float*)d_in[16];
    const float* o_b    = (const float*)d_in[17];
    const float* rms_w  = (const float*)d_in[18];
    const float* l1_w   = (const float*)d_in[19];
    const float* l1_b   = (const float*)d_in[20];
    const float* l2_w   = (const float*)d_in[21];
    const float* l2_b   = (const float*)d_in[22];
    const float* n1_w   = (const float*)d_in[23];
    const float* n1_b   = (const float*)d_in[24];
    const float* n2_w   = (const float*)d_in[25];
    const float* n2_b   = (const float*)d_in[26];
    (void)in_sizes; (void)n_in; (void)out_size;

    // Arena (floats), same 53,231,616-float footprint as previous version:
    // pos | P0:a3d | P1:Cxt/Hot | P2:Ho | P3:Fv/out2 | P4:xqt/Gat/ffn0 |
    // P5:a4t_h/Dq/ffn1 | P6:a4t_l/Ek/ffn2 | P7:ffn3 | kvp(+convW) | kvb
    // weights(q..l2) live in the pos region after conv-gemm consumes pos.
    float* ws  = (float*)d_ws;
    float* pos = ws;
    float* P0  = ws + 802816;
    float* P1  = P0 + MATF;
    float* P2  = P1 + MATF;
    float* P3  = P2 + MATF;
    float* P4  = P3 + MATF;
    float* P5  = P4 + MATF;
    float* P6  = P5 + MATF;
    float* P7  = P6 + MATF;
    float* kvp = P7 + MATF;
    float* kvb = kvp + 917504;
    if (ws_size < (size_t)53231616 * 4) return;

    us* xqt_h = (us*)P4;  us* xqt_l = xqt_h + MATF;
    us* a4t_h = (us*)P5;  us* a4t_l = (us*)P6;
    us* Cxt_h = (us*)P1;  us* Cxt_l = Cxt_h + MATF;
    us* Gat_h = (us*)P4;  us* Gat_l = Gat_h + MATF;
    us* Hot_h = (us*)P1;  us* Hot_l = Hot_h + MATF;
    us* ffn_h = (us*)P4;  us* ffn_l = (us*)P6;     // each spans 2 regions (25088x1024)
    float* Dq = P5;
    float* Ek = P6;
    float* Fv = P3;
    float* Ho = P2;
    us* wb   = (us*)pos;                           // q,k,v,o,l1,l2 hi/lo after conv-gemm
    us* wc_h = (us*)kvp;  us* wc_l = wc_h + 131072;

    pos_k  <<<256, 256, 0, stream>>>(pos);
    wconv1_k<<<64, 256, 0, stream>>>(conv_w, wc_h, wc_l);
    tconv_k<<<dim3(49, 8, 8), 256, 0, stream>>>(a4, a4t_h, a4t_l, 512, 3136);
    pool_k <<<784, 256, 0, stream>>>(a3, pos, P0, xqt_h, xqt_l);
    gemm_mf<GE_CONVT><<<784, 256, 0, stream>>>(wc_h, wc_l, a4t_h, a4t_l,
        nullptr, Cxt_h, Cxt_l, conv_b, bn_w, bn_b, pos, 512, 1, 256);
    wconv6_k<<<384, 256, 0, stream>>>(q_w, k_w, v_w, o_w, l1_w, l2_w, wb);
    gemm_mf<GE_F32><<<784, 256, 0, stream>>>(wb, wb + 65536, xqt_h, xqt_l,
        Dq, nullptr, nullptr, q_b, nullptr, nullptr, nullptr, 256, 1, 256);
    ln_l2_k<<<392, 256, 0, stream>>>(Dq, q_ln_w, q_ln_b);
    gemm_mf<GE_F32><<<784, 256, 0, stream>>>(wb + 131072, wb + 196608, Cxt_h, Cxt_l,
        Ek, nullptr, nullptr, k_b, nullptr, nullptr, nullptr, 256, 1, 256);
    ln_l2_k<<<392, 256, 0, stream>>>(Ek, k_ln_w, k_ln_b);
    gemm_mf<GE_F32><<<784, 256, 0, stream>>>(wb + 262144, wb + 327680, Cxt_h, Cxt_l,
        Fv, nullptr, nullptr, v_b, nullptr, nullptr, nullptr, 256, 1, 256);
    kv_part_k<<<dim3(7, 64), 256, 0, stream>>>(Ek, Fv, kvp);
    kv_red_k<<<512, 256, 0, stream>>>(kvp, kvb);
    attn_k<<<dim3(13, 8, 8), 256, 0, stream>>>(Dq, kvb, rms_w, Gat_h, Gat_l);
    gemm_mf<GE_F32><<<784, 256, 0, stream>>>(wb + 393216, wb + 458752, Gat_h, Gat_l,
        Ho, nullptr, nullptr, o_b, nullptr, nullptr, nullptr, 256, 1, 256);
    ln_res_k<1><<<392, 256, 0, stream>>>(Ho, P0, n1_w, n1_b, Hot_h, Hot_l);
    gemm_mf<GE_GELUT><<<3136, 256, 0, stream>>>(wb + 524288, wb + 786432, Hot_h, Hot_l,
        nullptr, ffn_h, ffn_l, l1_b, nullptr, nullptr, nullptr, 256, 3, 1024);
    gemm_mf<GE_F32><<<784, 256, 0, stream>>>(wb + 1048576, wb + 1310720, ffn_h, ffn_l,
        Fv, nullptr, nullptr, l2_b, nullptr, nullptr, nullptr, 1024, 1, 256);
    ln_res_k<0><<<392, 256, 0, stream>>>(Fv, Ho, n2_w, n2_b, nullptr, nullptr);
    up_a3_k<<<100352, 256, 0, stream>>>(Fv, a3, (float*)d_out);
    up_a4_k<<<200704, 256, 0, stream>>>(a4, (float*)d_out + 25690112);
}

// Round 3
// 1101.851 us; speedup vs baseline: 1.3222x; 1.0740x over previous
//
#include <hip/hip_runtime.h>
#include <math.h>

// Problem constants (idx == 10 branch; shapes fixed by setup_inputs)
#define L_    3136          // 56*56
#define R_    25088         // 8*L
#define C_    256
#define MATF  6422528       // 256 * R_

typedef __attribute__((ext_vector_type(8))) short s16x8;
typedef __attribute__((ext_vector_type(4))) float f32x4;
typedef unsigned short us;

// ---------- bf16 split helpers ----------
__device__ __forceinline__ us bfh(float v) {
    unsigned u = __float_as_uint(v);
    u = (u + 0x7FFFu + ((u >> 16) & 1u)) >> 16;   // RNE
    return (us)u;
}
__device__ __forceinline__ float bf2f(us h) { return __uint_as_float((unsigned)h << 16); }
__device__ __forceinline__ void split2(float v, us& h, us& l) {
    h = bfh(v);
    l = bfh(v - bf2f(h));
}
__device__ __forceinline__ uint4 packu4(const us* s) {
    uint4 u;
    u.x = (unsigned)s[0] | ((unsigned)s[1] << 16);
    u.y = (unsigned)s[2] | ((unsigned)s[3] << 16);
    u.z = (unsigned)s[4] | ((unsigned)s[5] << 16);
    u.w = (unsigned)s[6] | ((unsigned)s[7] << 16);
    return u;
}
__device__ __forceinline__ uint2 packu2(const us* s) {
    uint2 u;
    u.x = (unsigned)s[0] | ((unsigned)s[1] << 16);
    u.y = (unsigned)s[2] | ((unsigned)s[3] << 16);
    return u;
}

// async global->LDS 16B (wave-uniform base + lane*16 dest; integer detour for AS casts)
__device__ __forceinline__ void gl16(const us* g, const us* l) {
    __builtin_amdgcn_global_load_lds(
        (const __attribute__((address_space(1))) unsigned int*)(unsigned long long)(const void*)g,
        (__attribute__((address_space(3))) unsigned int*)(unsigned int)(unsigned long long)(const void*)l,
        16, 0, 0);
}

// 2-bit XOR swizzle of granule index (8 bf16 = 16B granules) within aligned-4 groups
__device__ __forceinline__ int swz2(int g, int s2) {
    return (g & ~3) | ((g ^ s2) & 3);
}

// ---------- weight convert: fp32 [M][K] -> swizzled bf16 hi/lo [M][K] ----------
__device__ __forceinline__ void wconv_body(const float* __restrict__ src,
        us* __restrict__ dh, us* __restrict__ dl, int idx, int kgs, int K)
{
    int m  = idx >> kgs;
    int gk = idx & ((1 << kgs) - 1);
    const float* sp = src + (size_t)m * K + gk * 8;
    float4 v0 = *(const float4*)sp;
    float4 v1 = *(const float4*)(sp + 4);
    float vv[8] = {v0.x, v0.y, v0.z, v0.w, v1.x, v1.y, v1.z, v1.w};
    us hh[8], ll[8];
    #pragma unroll
    for (int e = 0; e < 8; e++) split2(vv[e], hh[e], ll[e]);
    int p = swz2(gk, (m >> 1) & 3);
    size_t off = (size_t)m * K + (size_t)p * 8;
    *(uint4*)(dh + off) = packu4(hh);
    *(uint4*)(dl + off) = packu4(ll);
}

__global__ __launch_bounds__(256)
void wconv1_k(const float* __restrict__ w, us* __restrict__ dh, us* __restrict__ dl)
{   // conv_w: M=256 K=512 -> 16384 granules -> 64 blocks
    wconv_body(w, dh, dl, blockIdx.x * 256 + threadIdx.x, 6, 512);
}

__global__ __launch_bounds__(256)
void wconv6_k(const float* __restrict__ q, const float* __restrict__ k,
              const float* __restrict__ v, const float* __restrict__ o,
              const float* __restrict__ l1, const float* __restrict__ l2,
              us* __restrict__ wb)
{
    int bid = blockIdx.x;
    const float* src; us* dh; us* dl; int kgs, K;
    if (bid < 32)       { src = q;  dh = wb;           dl = wb + 65536;   kgs = 5; K = 256;  }
    else if (bid < 64)  { src = k;  dh = wb + 131072;  dl = wb + 196608;  kgs = 5; K = 256;  bid -= 32;  }
    else if (bid < 96)  { src = v;  dh = wb + 262144;  dl = wb + 327680;  kgs = 5; K = 256;  bid -= 64;  }
    else if (bid < 128) { src = o;  dh = wb + 393216;  dl = wb + 458752;  kgs = 5; K = 256;  bid -= 96;  }
    else if (bid < 256) { src = l1; dh = wb + 524288;  dl = wb + 786432;  kgs = 5; K = 256;  bid -= 128; }
    else                { src = l2; dh = wb + 1048576; dl = wb + 1310720; kgs = 7; K = 1024; bid -= 256; }
    wconv_body(src, dh, dl, bid * 256 + threadIdx.x, kgs, K);
}

// ---------- transpose-convert: fp32 [nb][C][Lb] -> swizzled bf16 hi/lo [nb*Lb][C] ----------
__global__ __launch_bounds__(256)
void tconv_k(const float* __restrict__ src, us* __restrict__ dh, us* __restrict__ dl,
             int C, int Lb)
{
    __shared__ float tl[64][68];
    int l0 = blockIdx.x * 64, c0 = blockIdx.y * 64, b = blockIdx.z;
    int t = threadIdx.x;
    {
        int cl = t >> 2, qq = t & 3;
        const float* sp = src + ((size_t)b * C + c0 + cl) * Lb + l0 + qq * 16;
        #pragma unroll
        for (int i = 0; i < 4; i++) {
            float4 v = *(const float4*)(sp + i * 4);
            *(float4*)&tl[cl][qq * 16 + i * 4] = v;
        }
    }
    __syncthreads();
    int rl = t & 63, cq = t >> 6;          // lanes over rows: conflict-free LDS column reads
    size_t r = (size_t)b * Lb + l0 + rl;
    int s2 = ((l0 + rl) >> 1) & 3;
    size_t rowo = r * (size_t)C;
    #pragma unroll
    for (int half = 0; half < 2; half++) {
        us hh[8], ll[8];
        #pragma unroll
        for (int e = 0; e < 8; e++)
            split2(tl[cq * 16 + half * 8 + e][rl], hh[e], ll[e]);
        int gfull = (c0 >> 3) + cq * 2 + half;
        int p = swz2(gfull, s2);
        *(uint4*)(dh + rowo + (size_t)p * 8) = packu4(hh);
        *(uint4*)(dl + rowo + (size_t)p * 8) = packu4(ll);
    }
}

// ---------- MFMA split-bf16 GEMM: C[m][r] = W[m][:] . Xt[r][:] ----------
// Double-buffered GBK=32, prefetch-before-compute, one barrier per K-step.
#define GBM 128
#define GBN 64
#define GBK 32
enum { GE_F32 = 0, GE_CONVT = 1, GE_GELUT = 2 };

template<int EPI>
__global__ __launch_bounds__(256)
void gemm_mf(const us* __restrict__ Wh, const us* __restrict__ Wl,
             const us* __restrict__ Xh, const us* __restrict__ Xl,
             float* __restrict__ Yf, us* __restrict__ Yth, us* __restrict__ Ytl,
             const float* __restrict__ bias, const float* __restrict__ bnw,
             const float* __restrict__ bnb, const float* __restrict__ pos,
             int K, int mts, int Mrow)
{
    __shared__ us Ah[2][GBM * GBK];
    __shared__ us Al[2][GBM * GBK];
    __shared__ us Bh[2][GBN * GBK];
    __shared__ us Bl[2][GBN * GBK];   // 48 KB total -> 3 blocks/CU

    const int tid = threadIdx.x;
    // XCD-bijective remap (nwg % 8 == 0 for all launches), m-fastest for B-panel L2 reuse
    int nwg = gridDim.x;
    int wg = (blockIdx.x & 7) * (nwg >> 3) + (blockIdx.x >> 3);
    int mt = wg & ((1 << mts) - 1);
    int rt = wg >> mts;
    const int m0 = mt * GBM;
    const int r0 = rt * GBN;

    const us* Ahg = Wh + (size_t)m0 * K;
    const us* Alg = Wl + (size_t)m0 * K;
    const us* Bhg = Xh + (size_t)r0 * K;
    const us* Blg = Xl + (size_t)r0 * K;

    const int lane = tid & 63;
    const int w    = tid >> 6;
    const int wm   = (w >> 1) * 64;
    const int wr   = (w & 1) * 32;
    const int l15  = lane & 15;
    const int lg   = lane >> 4;
    const int s2k  = (l15 >> 1) & 3;
    const int koff = ((lg ^ s2k) & 3) << 3;      // swizzled 16B slot within 32-el row

    const int asub = (tid & 3) << 3;
    const int brow = tid >> 2, bsub = (tid & 3) << 3;

    f32x4 acc[4][2];
    #pragma unroll
    for (int a = 0; a < 4; a++)
        #pragma unroll
        for (int b = 0; b < 2; b++)
            acc[a][b] = (f32x4){0.f, 0.f, 0.f, 0.f};

    const int nst = K >> 5;

    #define STAGE(buf, k0)                                                        \
    {                                                                             \
        _Pragma("unroll")                                                         \
        for (int q = 0; q < 2; q++) {                                             \
            int g = q * 256 + tid;                                                \
            int row = g >> 2;                                                     \
            gl16(Ahg + (size_t)row * K + (k0) + asub, &Ah[buf][g * 8]);           \
            gl16(Alg + (size_t)row * K + (k0) + asub, &Al[buf][g * 8]);           \
        }                                                                         \
        gl16(Bhg + (size_t)brow * K + (k0) + bsub, &Bh[buf][tid * 8]);            \
        gl16(Blg + (size_t)brow * K + (k0) + bsub, &Bl[buf][tid * 8]);            \
    }

    STAGE(0, 0);
    __syncthreads();
    int cur = 0;
    for (int s = 0; s < nst; s++) {
        if (s + 1 < nst) STAGE(cur ^ 1, (s + 1) << 5);
        const us* AHc = &Ah[cur][0];
        const us* ALc = &Al[cur][0];
        const us* BHc = &Bh[cur][0];
        const us* BLc = &Bl[cur][0];
        s16x8 va[4], wa[4], vb[2], ub[2];
        #pragma unroll
        for (int a = 0; a < 4; a++) {
            int off = (wm + a * 16 + l15) * GBK + koff;
            va[a] = *(const s16x8*)(AHc + off);
            wa[a] = *(const s16x8*)(ALc + off);
        }
        #pragma unroll
        for (int b = 0; b < 2; b++) {
            int off = (wr + b * 16 + l15) * GBK + koff;
            vb[b] = *(const s16x8*)(BHc + off);
            ub[b] = *(const s16x8*)(BLc + off);
        }
        #pragma unroll
        for (int a = 0; a < 4; a++)
            #pragma unroll
            for (int b = 0; b < 2; b++) {
                acc[a][b] = __builtin_amdgcn_mfma_f32_16x16x32_bf16(va[a], vb[b], acc[a][b], 0, 0, 0);
                acc[a][b] = __builtin_amdgcn_mfma_f32_16x16x32_bf16(va[a], ub[b], acc[a][b], 0, 0, 0);
                acc[a][b] = __builtin_amdgcn_mfma_f32_16x16x32_bf16(wa[a], vb[b], acc[a][b], 0, 0, 0);
            }
        __syncthreads();
        cur ^= 1;
    }
    #undef STAGE

    // epilogue: D row=(lane>>4)*4+reg (m-dim), col=lane&15 (r-dim)
    if (EPI == GE_F32) {
        #pragma unroll
        for (int a = 0; a < 4; a++) {
            int mb = m0 + wm + a * 16 + lg * 4;
            #pragma unroll
            for (int b = 0; b < 2; b++) {
                int rr = r0 + wr + b * 16 + l15;
                #pragma unroll
                for (int q = 0; q < 4; q++)
                    Yf[(size_t)(mb + q) * R_ + rr] = acc[a][b][q] + bias[mb + q];
            }
        }
    } else {
        #pragma unroll
        for (int b = 0; b < 2; b++) {
            int rr = r0 + wr + b * 16 + l15;
            int s2r = (rr >> 1) & 3;
            int l = rr % L_;
            size_t rowo = (size_t)rr * Mrow;
            #pragma unroll
            for (int a = 0; a < 4; a++) {
                int mb = m0 + wm + a * 16 + lg * 4;
                us hh[4], ll[4];
                #pragma unroll
                for (int q = 0; q < 4; q++) {
                    int m = mb + q;
                    float v = acc[a][b][q] + bias[m];
                    if (EPI == GE_CONVT) {
                        v = v * 0.9999950000374997f * bnw[m] + bnb[m];
                        v += pos[(size_t)m * L_ + l];
                    } else {
                        v = 0.5f * v * (1.f + erff(v * 0.7071067811865475f));
                    }
                    split2(v, hh[q], ll[q]);
                }
                int p = swz2(mb >> 3, s2r);
                size_t off = rowo + (size_t)((p << 3) | (mb & 7));
                *(uint2*)(Yth + off) = packu2(hh);
                *(uint2*)(Ytl + off) = packu2(ll);
            }
        }
    }
}

// pos[c][l]: c<64: sin(y*om) | <128: cos(y*om) | <192: sin(x*om) | <256: cos(x*om)
__global__ __launch_bounds__(256)
void pos_k(float* __restrict__ pos)
{
    int c = blockIdx.x;
    int q = c >> 6, t = c & 63;
    float om = exp2f(-(float)t * (13.287712379549449f / 64.f));  // 10000^(-t/64)
    for (int l = threadIdx.x; l < L_; l += 256) {
        int y = l / 56, x = l - y * 56;
        float arg = (q < 2 ? (float)y : (float)x) * om;
        pos[(size_t)c * L_ + l] = (q & 1) ? cosf(arg) : sinf(arg);
    }
}

// avgpool2(a3) -> a3d (fp32 residual) and xq_t = bf16T(a3d + pos) (swizzled)
__global__ __launch_bounds__(256)
void pool_k(const float* __restrict__ a3, const float* __restrict__ pos,
            float* __restrict__ a3d, us* __restrict__ xh, us* __restrict__ xl)
{
    __shared__ us hi[256][34];
    __shared__ us lo[256][34];
    int blk = blockIdx.x;                 // 784 = 8b * 98 lblk
    int b = blk / 98, l0 = (blk % 98) * 32;
    int t = threadIdx.x;
    {
        int lt = t & 31, cg = t >> 5;
        int l = l0 + lt;
        int y = l / 56, x = l - y * 56;
        const float* srow = a3 + ((size_t)b * 256) * 12544 + (2 * y) * 112 + 2 * x;
        float* drow = a3d + (size_t)b * L_ + l;
        const float* prow = pos + l;
        for (int cc = 0; cc < 32; cc++) {
            int c = cc * 8 + cg;
            const float* sp = srow + (size_t)c * 12544;
            float2 v0 = *(const float2*)sp;
            float2 v1 = *(const float2*)(sp + 112);
            float v = (v0.x + v0.y + v1.x + v1.y) * 0.25f;
            drow[(size_t)c * R_] = v;
            split2(v + prow[(size_t)c * L_], hi[c][lt], lo[c][lt]);
        }
    }
    __syncthreads();
    int j = t & 31, cq = t >> 5;
    int r = b * L_ + l0 + j;
    int s2 = ((l0 + j) >> 1) & 3;
    size_t rowo = (size_t)r * 256;
    #pragma unroll
    for (int gg = 0; gg < 4; gg++) {
        int cb = cq * 32 + gg * 8;
        us hh[8], ll[8];
        #pragma unroll
        for (int e = 0; e < 8; e++) { hh[e] = hi[cb + e][j]; ll[e] = lo[cb + e][j]; }
        int p = swz2((cq << 2) | gg, s2);
        *(uint4*)(xh + rowo + (size_t)p * 8) = packu4(hh);
        *(uint4*)(xl + rowo + (size_t)p * 8) = packu4(ll);
    }
}

// In-place LayerNorm (eps 1e-5) over channel dim then l2-normalize (max(n,1e-4)).
// Values cached in registers: one global read pass instead of three.
__global__ __launch_bounds__(256)
void ln_l2_k(float* __restrict__ X, const float* __restrict__ wt, const float* __restrict__ bt)
{
    __shared__ float red[4][64];
    __shared__ float red2[4][64];
    int tid = threadIdx.x;
    int rr = tid & 63, og = tid >> 6;
    size_t r = (size_t)blockIdx.x * 64 + rr;
    float vv[64];
    float s1 = 0.f, s2 = 0.f;
    for (int j = 0; j < 64; j++) {
        float v = X[(size_t)(og * 64 + j) * R_ + r];
        vv[j] = v;
        s1 += v; s2 = fmaf(v, v, s2);
    }
    red[og][rr] = s1; red2[og][rr] = s2;
    __syncthreads();
    float mu  = (red[0][rr] + red[1][rr] + red[2][rr] + red[3][rr]) * (1.f / 256.f);
    float var = (red2[0][rr] + red2[1][rr] + red2[2][rr] + red2[3][rr]) * (1.f / 256.f) - mu * mu;
    float rstd = rsqrtf(var + 1e-5f);
    __syncthreads();                       // protect red before reuse
    float t2 = 0.f;
    for (int j = 0; j < 64; j++) {
        int o = og * 64 + j;
        float y = (vv[j] - mu) * rstd * wt[o] + bt[o];
        t2 = fmaf(y, y, t2);
    }
    red[og][rr] = t2;
    __syncthreads();
    float nrm = sqrtf(red[0][rr] + red[1][rr] + red[2][rr] + red[3][rr]);
    float scale = 1.f / fmaxf(nrm, 1e-4f);
    for (int j = 0; j < 64; j++) {
        int o = og * 64 + j;
        size_t ix = (size_t)o * R_ + r;
        X[ix] = (vv[j] - mu) * rstd * wt[o] * scale + bt[o] * scale;
    }
}

// In-place X = res + LayerNorm(X); optionally also bf16T swizzled copy for next GEMM
template<int TOUT>
__global__ __launch_bounds__(256)
void ln_res_k(float* __restrict__ X, const float* __restrict__ res,
              const float* __restrict__ wt, const float* __restrict__ bt,
              us* __restrict__ th, us* __restrict__ tl_)
{
    __shared__ float red[4][64];
    __shared__ float red2[4][64];
    int tid = threadIdx.x;
    int rr = tid & 63, og = tid >> 6;
    size_t r = (size_t)blockIdx.x * 64 + rr;
    float s1 = 0.f, s2 = 0.f;
    for (int j = 0; j < 64; j++) {
        float v = X[(size_t)(og * 64 + j) * R_ + r];
        s1 += v; s2 = fmaf(v, v, s2);
    }
    red[og][rr] = s1; red2[og][rr] = s2;
    __syncthreads();
    float mu  = (red[0][rr] + red[1][rr] + red[2][rr] + red[3][rr]) * (1.f / 256.f);
    float var = (red2[0][rr] + red2[1][rr] + red2[2][rr] + red2[3][rr]) * (1.f / 256.f) - mu * mu;
    float rstd = rsqrtf(var + 1e-5f);
    float yv[64];
    #pragma unroll
    for (int j = 0; j < 64; j++) {
        int o = og * 64 + j;
        size_t ix = (size_t)o * R_ + r;
        float v = X[ix];
        float y = res[ix] + (v - mu) * rstd * wt[o] + bt[o];
        X[ix] = y;
        yv[j] = y;
    }
    if (TOUT) {
        int s2r = ((int)r >> 1) & 3;
        size_t rowo = r * 256;
        #pragma unroll
        for (int g = 0; g < 8; g++) {
            us hh[8], ll[8];
            #pragma unroll
            for (int e = 0; e < 8; e++) split2(yv[g * 8 + e], hh[e], ll[e]);
            int p = swz2((og << 3) | g, s2r);
            *(uint4*)(th  + rowo + (size_t)p * 8) = packu4(hh);
            *(uint4*)(tl_ + rowo + (size_t)p * 8) = packu4(ll);
        }
    }
}

// Partial KV: kvp[n][slab][d][m] = sum_{l in slab} (d<32?cw:sw)[l]*K[l][d&31]*V[l][m]
__global__ __launch_bounds__(256)
void kv_part_k(const float* __restrict__ Kt, const float* __restrict__ Vt,
               float* __restrict__ kvp)
{
    __shared__ float kl[64][33];
    __shared__ float vl[64][33];
    __shared__ float cwl[64], swl[64];
    int slab = blockIdx.x;
    int n = blockIdx.y;
    int b = n >> 3, h = n & 7;
    int tid = threadIdx.x;
    int lane = tid & 63, grp = tid >> 6;
    int d = tid >> 2;
    int m0 = (tid & 3) * 8;
    float acc[8] = {0,0,0,0,0,0,0,0};
    size_t base = (size_t)(h * 32) * R_ + (size_t)b * L_;
    for (int ch = 0; ch < 7; ch++) {
        int l0 = slab * 448 + ch * 64;
        #pragma unroll
        for (int j = 0; j < 8; j++) {
            int dd = grp * 8 + j;
            kl[lane][dd] = Kt[base + (size_t)dd * R_ + l0 + lane];
            vl[lane][dd] = Vt[base + (size_t)dd * R_ + l0 + lane];
        }
        if (tid < 64) {
            float wi = (float)(l0 + tid + 1) * (1.f / 3136.f);
            cwl[tid] = cosf(wi); swl[tid] = sinf(wi);
        }
        __syncthreads();
        for (int l = 0; l < 64; l++) {
            float kvv = (d < 32 ? cwl[l] : swl[l]) * kl[l][d & 31];
            #pragma unroll
            for (int j = 0; j < 8; j++)
                acc[j] = fmaf(kvv, vl[l][m0 + j], acc[j]);
        }
        __syncthreads();
    }
    float* out = kvp + ((size_t)(n * 7 + slab)) * 2048 + d * 32 + m0;
    #pragma unroll
    for (int j = 0; j < 8; j++) out[j] = acc[j];
}

__global__ __launch_bounds__(256)
void kv_red_k(const float* __restrict__ kvp, float* __restrict__ kv)
{
    int idx = blockIdx.x * 256 + threadIdx.x;
    int n = idx >> 11, dm = idx & 2047;
    float s = 0.f;
    #pragma unroll
    for (int t = 0; t < 7; t++) s += kvp[((size_t)(n * 7 + t)) * 2048 + dm];
    kv[idx] = s;
}

// attn -> rmsnorm -> bf16T swizzled output [r][c=h*32+m]
__global__ __launch_bounds__(256)
void attn_k(const float* __restrict__ Q, const float* __restrict__ kv,
            const float* __restrict__ rmsw, us* __restrict__ Gh, us* __restrict__ Gl)
{
    __shared__ float kvl[2048];
    int h = blockIdx.y, b = blockIdx.z;
    int tid = threadIdx.x;
    int n = b * 8 + h;
    for (int i = tid; i < 2048; i += 256) kvl[i] = kv[(size_t)n * 2048 + i];
    __syncthreads();
    int l = blockIdx.x * 256 + tid;
    if (l >= L_) return;
    size_t r = (size_t)b * L_ + l;
    float qd[32];
    #pragma unroll
    for (int dd = 0; dd < 32; dd++) qd[dd] = Q[((size_t)(h * 32 + dd)) * R_ + r];
    float wi = (float)(l + 1) * (1.f / 3136.f);
    float cw = cosf(wi), sw = sinf(wi);
    float val[32]; float ss = 0.f;
    #pragma unroll
    for (int m = 0; m < 32; m++) {
        float s1 = 0.f, s2 = 0.f;
        #pragma unroll
        for (int dd = 0; dd < 32; dd++) {
            s1 = fmaf(qd[dd], kvl[dd * 32 + m], s1);
            s2 = fmaf(qd[dd], kvl[(dd + 32) * 32 + m], s2);
        }
        float v = cw * s1 + sw * s2;
        val[m] = v; ss = fmaf(v, v, ss);
    }
    float rinv = rsqrtf(ss * (1.f / 32.f) + 1e-6f);
    int s2w = (l >> 1) & 3;
    size_t rowo = r * 256;
    #pragma unroll
    for (int j = 0; j < 4; j++) {
        us hh[8], ll[8];
        #pragma unroll
        for (int e = 0; e < 8; e++) {
            float y = rmsw[j * 8 + e] * val[j * 8 + e] * rinv;
            split2(y, hh[e], ll[e]);
        }
        int p = swz2((h << 2) | j, s2w);
        *(uint4*)(Gh + rowo + (size_t)p * 8) = packu4(hh);
        *(uint4*)(Gl + rowo + (size_t)p * 8) = packu4(ll);
    }
}

// ---------- 2x upsample (align_corners=False): one thread -> 2x2 output quad ----------
// xo=2k: 0.25*v[k-1]+0.75*v[k];  xo=2k+1: 0.75*v[k]+0.25*v[k+1]  (clamped)
__global__ __launch_bounds__(256)
void up_a3_k(const float* __restrict__ out2, const float* __restrict__ a3,
             float* __restrict__ out)
{
    unsigned idx = blockIdx.x * 256u + threadIdx.x;   // < 6422528
    int k = idx % 56;
    unsigned t1 = idx / 56;
    int j = t1 % 56;
    unsigned t2 = t1 / 56;
    int c = t2 & 255;
    int b = t2 >> 8;
    int km = k > 0 ? k - 1 : 0, kp = k < 55 ? k + 1 : 55;
    int jm = j > 0 ? j - 1 : 0, jp = j < 55 ? j + 1 : 55;
    const float* src = out2 + (size_t)c * R_ + (size_t)b * L_;
    const float* r0 = src + jm * 56;
    const float* r1 = src + j  * 56;
    const float* r2 = src + jp * 56;
    float h00 = fmaf(0.25f, r0[km], 0.75f * r0[k]);
    float h01 = fmaf(0.25f, r0[kp], 0.75f * r0[k]);
    float h10 = fmaf(0.25f, r1[km], 0.75f * r1[k]);
    float h11 = fmaf(0.25f, r1[kp], 0.75f * r1[k]);
    float h20 = fmaf(0.25f, r2[km], 0.75f * r2[k]);
    float h21 = fmaf(0.25f, r2[kp], 0.75f * r2[k]);
    float o00 = fmaf(0.25f, h00, 0.75f * h10);
    float o01 = fmaf(0.25f, h01, 0.75f * h11);
    float o10 = fmaf(0.25f, h20, 0.75f * h10);
    float o11 = fmaf(0.25f, h21, 0.75f * h11);
    size_t obase = (((size_t)(b * 256 + c) * 112) + 2 * j) * 112 + 2 * k;
    const float* ap = a3 + obase;
    float2 a0 = *(const float2*)ap;
    float2 a1 = *(const float2*)(ap + 112);
    float2 w0 = {o00 * a0.x, o01 * a0.y};
    float2 w1 = {o10 * a1.x, o11 * a1.y};
    *(float2*)(out + obase) = w0;
    *(float2*)(out + obase + 112) = w1;
}

__global__ __launch_bounds__(256)
void up_a4_k(const float* __restrict__ a4, float* __restrict__ out)
{
    unsigned idx = blockIdx.x * 256u + threadIdx.x;   // < 12845056
    int k = idx % 56;
    unsigned t1 = idx / 56;
    int j = t1 % 56;
    unsigned t2 = t1 / 56;
    int c = t2 & 511;
    int b = t2 >> 9;
    int km = k > 0 ? k - 1 : 0, kp = k < 55 ? k + 1 : 55;
    int jm = j > 0 ? j - 1 : 0, jp = j < 55 ? j + 1 : 55;
    const float* src = a4 + (size_t)(b * 512 + c) * 3136;
    const float* r0 = src + jm * 56;
    const float* r1 = src + j  * 56;
    const float* r2 = src + jp * 56;
    float h00 = fmaf(0.25f, r0[km], 0.75f * r0[k]);
    float h01 = fmaf(0.25f, r0[kp], 0.75f * r0[k]);
    float h10 = fmaf(0.25f, r1[km], 0.75f * r1[k]);
    float h11 = fmaf(0.25f, r1[kp], 0.75f * r1[k]);
    float h20 = fmaf(0.25f, r2[km], 0.75f * r2[k]);
    float h21 = fmaf(0.25f, r2[kp], 0.75f * r2[k]);
    float o00 = fmaf(0.25f, h00, 0.75f * h10);
    float o01 = fmaf(0.25f, h01, 0.75f * h11);
    float o10 = fmaf(0.25f, h20, 0.75f * h10);
    float o11 = fmaf(0.25f, h21, 0.75f * h11);
    size_t obase = (((size_t)(b * 512 + c) * 112) + 2 * j) * 112 + 2 * k;
    *(float2*)(out + obase) = (float2){o00, o01};
    *(float2*)(out + obase + 112) = (float2){o10, o11};
}

extern "C" void kernel_launch(void* const* d_in, const int* in_sizes, int n_in,
                              void* d_out, int out_size, void* d_ws, size_t ws_size,
                              hipStream_t stream)
{
    const float* a3     = (const float*)d_in[0];
    const float* a4     = (const float*)d_in[1];
    const float* conv_w = (const float*)d_in[2];
    const float* conv_b = (const float*)d_in[3];
    const float* bn_w   = (const float*)d_in[4];
    const float* bn_b   = (const float*)d_in[5];
    const float* q_w    = (const float*)d_in[6];
    const float* q_b    = (const float*)d_in[7];
    const float* q_ln_w = (const float*)d_in[8];
    const float* q_ln_b = (const float*)d_in[9];
    const float* k_w    = (const float*)d_in[10];
    const float* k_b    = (const float*)d_in[11];
    const float* k_ln_w = (const float*)d_in[12];
    const float* k_ln_b = (const float*)d_in[13];
    const float* v_w    = (const float*)d_in[14];
    const float* v_b    = (const float*)d_in[15];
    const float* o_w    = (const float*)d_in[16];
    const float* o_b    = (const float*)d_in[17];
    const float* rms_w  = (const float*)d_in[18];
    const float* l1_w   = (const float*)d_in[19];
    const float* l1_b   = (const float*)d_in[20];
    const float* l2_w   = (const float*)d_in[21];
    const float* l2_b   = (const float*)d_in[22];
    const float* n1_w   = (const float*)d_in[23];
    const float* n1_b   = (const float*)d_in[24];
    const float* n2_w   = (const float*)d_in[25];
    const float* n2_b   = (const float*)d_in[26];
    (void)in_sizes; (void)n_in; (void)out_size;

    // Arena (floats), same 53,231,616-float footprint:
    // pos | P0:a3d | P1:Cxt/Hot | P2:Ho | P3:Fv/out2 | P4:xqt/Gat/ffn0 |
    // P5:a4t_h/Dq/ffn1 | P6:a4t_l/Ek/ffn2 | P7:ffn3 | kvp(+convW) | kvb
    float* ws  = (float*)d_ws;
    float* pos = ws;
    float* P0  = ws + 802816;
    float* P1  = P0 + MATF;
    float* P2  = P1 + MATF;
    float* P3  = P2 + MATF;
    float* P4  = P3 + MATF;
    float* P5  = P4 + MATF;
    float* P6  = P5 + MATF;
    float* P7  = P6 + MATF;
    float* kvp = P7 + MATF;
    float* kvb = kvp + 917504;
    if (ws_size < (size_t)53231616 * 4) return;

    us* xqt_h = (us*)P4;  us* xqt_l = xqt_h + MATF;
    us* a4t_h = (us*)P5;  us* a4t_l = (us*)P6;
    us* Cxt_h = (us*)P1;  us* Cxt_l = Cxt_h + MATF;
    us* Gat_h = (us*)P4;  us* Gat_l = Gat_h + MATF;
    us* Hot_h = (us*)P1;  us* Hot_l = Hot_h + MATF;
    us* ffn_h = (us*)P4;  us* ffn_l = (us*)P6;     // each spans 2 regions (25088x1024)
    float* Dq = P5;
    float* Ek = P6;
    float* Fv = P3;
    float* Ho = P2;
    us* wb   = (us*)pos;                           // q,k,v,o,l1,l2 hi/lo after conv-gemm
    us* wc_h = (us*)kvp;  us* wc_l = wc_h + 131072;

    pos_k  <<<256, 256, 0, stream>>>(pos);
    wconv1_k<<<64, 256, 0, stream>>>(conv_w, wc_h, wc_l);
    tconv_k<<<dim3(49, 8, 8), 256, 0, stream>>>(a4, a4t_h, a4t_l, 512, 3136);
    pool_k <<<784, 256, 0, stream>>>(a3, pos, P0, xqt_h, xqt_l);
    gemm_mf<GE_CONVT><<<784, 256, 0, stream>>>(wc_h, wc_l, a4t_h, a4t_l,
        nullptr, Cxt_h, Cxt_l, conv_b, bn_w, bn_b, pos, 512, 1, 256);
    wconv6_k<<<384, 256, 0, stream>>>(q_w, k_w, v_w, o_w, l1_w, l2_w, wb);
    gemm_mf<GE_F32><<<784, 256, 0, stream>>>(wb, wb + 65536, xqt_h, xqt_l,
        Dq, nullptr, nullptr, q_b, nullptr, nullptr, nullptr, 256, 1, 256);
    ln_l2_k<<<392, 256, 0, stream>>>(Dq, q_ln_w, q_ln_b);
    gemm_mf<GE_F32><<<784, 256, 0, stream>>>(wb + 131072, wb + 196608, Cxt_h, Cxt_l,
        Ek, nullptr, nullptr, k_b, nullptr, nullptr, nullptr, 256, 1, 256);
    ln_l2_k<<<392, 256, 0, stream>>>(Ek, k_ln_w, k_ln_b);
    gemm_mf<GE_F32><<<784, 256, 0, stream>>>(wb + 262144, wb + 327680, Cxt_h, Cxt_l,
        Fv, nullptr, nullptr, v_b, nullptr, nullptr, nullptr, 256, 1, 256);
    kv_part_k<<<dim3(7, 64), 256, 0, stream>>>(Ek, Fv, kvp);
    kv_red_k<<<512, 256, 0, stream>>>(kvp, kvb);
    attn_k<<<dim3(13, 8, 8), 256, 0, stream>>>(Dq, kvb, rms_w, Gat_h, Gat_l);
    gemm_mf<GE_F32><<<784, 256, 0, stream>>>(wb + 393216, wb + 458752, Gat_h, Gat_l,
        Ho, nullptr, nullptr, o_b, nullptr, nullptr, nullptr, 256, 1, 256);
    ln_res_k<1><<<392, 256, 0, stream>>>(Ho, P0, n1_w, n1_b, Hot_h, Hot_l);
    gemm_mf<GE_GELUT><<<3136, 256, 0, stream>>>(wb + 524288, wb + 786432, Hot_h, Hot_l,
        nullptr, ffn_h, ffn_l, l1_b, nullptr, nullptr, nullptr, 256, 3, 1024);
    gemm_mf<GE_F32><<<784, 256, 0, stream>>>(wb + 1048576, wb + 1310720, ffn_h, ffn_l,
        Fv, nullptr, nullptr, l2_b, nullptr, nullptr, nullptr, 1024, 1, 256);
    ln_res_k<0><<<392, 256, 0, stream>>>(Fv, Ho, n2_w, n2_b, nullptr, nullptr);
    up_a3_k<<<25088, 256, 0, stream>>>(Fv, a3, (float*)d_out);
    up_a4_k<<<50176, 256, 0, stream>>>(a4, (float*)d_out + 25690112);
}

// Round 4
// 1081.225 us; speedup vs baseline: 1.3474x; 1.0191x over previous
//
#include <hip/hip_runtime.h>
#include <math.h>

// Problem constants (idx == 10 branch; shapes fixed by setup_inputs)
#define L_    3136          // 56*56
#define R_    25088         // 8*L
#define C_    256
#define MATF  6422528       // 256 * R_

typedef __attribute__((ext_vector_type(8))) short s16x8;
typedef __attribute__((ext_vector_type(4))) float f32x4;
typedef unsigned short us;

// ---------- bf16 split helpers ----------
__device__ __forceinline__ us bfh(float v) {
    unsigned u = __float_as_uint(v);
    u = (u + 0x7FFFu + ((u >> 16) & 1u)) >> 16;   // RNE
    return (us)u;
}
__device__ __forceinline__ float bf2f(us h) { return __uint_as_float((unsigned)h << 16); }
__device__ __forceinline__ void split2(float v, us& h, us& l) {
    h = bfh(v);
    l = bfh(v - bf2f(h));
}
__device__ __forceinline__ uint4 packu4(const us* s) {
    uint4 u;
    u.x = (unsigned)s[0] | ((unsigned)s[1] << 16);
    u.y = (unsigned)s[2] | ((unsigned)s[3] << 16);
    u.z = (unsigned)s[4] | ((unsigned)s[5] << 16);
    u.w = (unsigned)s[6] | ((unsigned)s[7] << 16);
    return u;
}
__device__ __forceinline__ uint2 packu2(const us* s) {
    uint2 u;
    u.x = (unsigned)s[0] | ((unsigned)s[1] << 16);
    u.y = (unsigned)s[2] | ((unsigned)s[3] << 16);
    return u;
}

// async global->LDS 16B (wave-uniform base + lane*16 dest; integer detour for AS casts)
__device__ __forceinline__ void gl16(const us* g, const us* l) {
    __builtin_amdgcn_global_load_lds(
        (const __attribute__((address_space(1))) unsigned int*)(unsigned long long)(const void*)g,
        (__attribute__((address_space(3))) unsigned int*)(unsigned int)(unsigned long long)(const void*)l,
        16, 0, 0);
}

// 2-bit XOR swizzle of granule index (8 bf16 = 16B granules) within aligned-4 groups
__device__ __forceinline__ int swz2(int g, int s2) {
    return (g & ~3) | ((g ^ s2) & 3);
}

// ---------- weight convert: fp32 [M][K] -> swizzled bf16 hi/lo [M][K] ----------
__device__ __forceinline__ void wconv_body(const float* __restrict__ src,
        us* __restrict__ dh, us* __restrict__ dl, int idx, int kgs, int K)
{
    int m  = idx >> kgs;
    int gk = idx & ((1 << kgs) - 1);
    const float* sp = src + (size_t)m * K + gk * 8;
    float4 v0 = *(const float4*)sp;
    float4 v1 = *(const float4*)(sp + 4);
    float vv[8] = {v0.x, v0.y, v0.z, v0.w, v1.x, v1.y, v1.z, v1.w};
    us hh[8], ll[8];
    #pragma unroll
    for (int e = 0; e < 8; e++) split2(vv[e], hh[e], ll[e]);
    int p = swz2(gk, (m >> 1) & 3);
    size_t off = (size_t)m * K + (size_t)p * 8;
    *(uint4*)(dh + off) = packu4(hh);
    *(uint4*)(dl + off) = packu4(ll);
}

__global__ __launch_bounds__(256)
void wconv1_k(const float* __restrict__ w, us* __restrict__ dh, us* __restrict__ dl)
{   // conv_w: M=256 K=512 -> 16384 granules -> 64 blocks
    wconv_body(w, dh, dl, blockIdx.x * 256 + threadIdx.x, 6, 512);
}

__global__ __launch_bounds__(256)
void wconv6_k(const float* __restrict__ q, const float* __restrict__ k,
              const float* __restrict__ v, const float* __restrict__ o,
              const float* __restrict__ l1, const float* __restrict__ l2,
              us* __restrict__ wb)
{
    int bid = blockIdx.x;
    const float* src; us* dh; us* dl; int kgs, K;
    if (bid < 32)       { src = q;  dh = wb;           dl = wb + 65536;   kgs = 5; K = 256;  }
    else if (bid < 64)  { src = k;  dh = wb + 131072;  dl = wb + 196608;  kgs = 5; K = 256;  bid -= 32;  }
    else if (bid < 96)  { src = v;  dh = wb + 262144;  dl = wb + 327680;  kgs = 5; K = 256;  bid -= 64;  }
    else if (bid < 128) { src = o;  dh = wb + 393216;  dl = wb + 458752;  kgs = 5; K = 256;  bid -= 96;  }
    else if (bid < 256) { src = l1; dh = wb + 524288;  dl = wb + 786432;  kgs = 5; K = 256;  bid -= 128; }
    else                { src = l2; dh = wb + 1048576; dl = wb + 1310720; kgs = 7; K = 1024; bid -= 256; }
    wconv_body(src, dh, dl, bid * 256 + threadIdx.x, kgs, K);
}

// ---------- transpose-convert: fp32 [nb][C][Lb] -> swizzled bf16 hi/lo [nb*Lb][C] ----------
__global__ __launch_bounds__(256)
void tconv_k(const float* __restrict__ src, us* __restrict__ dh, us* __restrict__ dl,
             int C, int Lb)
{
    __shared__ float tl[64][68];
    int l0 = blockIdx.x * 64, c0 = blockIdx.y * 64, b = blockIdx.z;
    int t = threadIdx.x;
    {
        int cl = t >> 2, qq = t & 3;
        const float* sp = src + ((size_t)b * C + c0 + cl) * Lb + l0 + qq * 16;
        #pragma unroll
        for (int i = 0; i < 4; i++) {
            float4 v = *(const float4*)(sp + i * 4);
            *(float4*)&tl[cl][qq * 16 + i * 4] = v;
        }
    }
    __syncthreads();
    int rl = t & 63, cq = t >> 6;          // lanes over rows: conflict-free LDS column reads
    size_t r = (size_t)b * Lb + l0 + rl;
    int s2 = ((l0 + rl) >> 1) & 3;
    size_t rowo = r * (size_t)C;
    #pragma unroll
    for (int half = 0; half < 2; half++) {
        us hh[8], ll[8];
        #pragma unroll
        for (int e = 0; e < 8; e++)
            split2(tl[cq * 16 + half * 8 + e][rl], hh[e], ll[e]);
        int gfull = (c0 >> 3) + cq * 2 + half;
        int p = swz2(gfull, s2);
        *(uint4*)(dh + rowo + (size_t)p * 8) = packu4(hh);
        *(uint4*)(dl + rowo + (size_t)p * 8) = packu4(ll);
    }
}

// ---------- MFMA split-bf16 GEMM: C[m][r] = W[m][:] . Xt[r][:] ----------
// 128x128 tile, 8 waves (512 thr), double-buffered GBK=32, prefetch-early, 1 barrier/K-step.
#define GBM 128
#define GBN 128
#define GBK 32
enum { GE_F32 = 0, GE_CONVT = 1, GE_GELUT = 2 };

template<int EPI>
__global__ __launch_bounds__(512)
void gemm_mf(const us* __restrict__ Wh, const us* __restrict__ Wl,
             const us* __restrict__ Xh, const us* __restrict__ Xl,
             float* __restrict__ Yf, us* __restrict__ Yth, us* __restrict__ Ytl,
             const float* __restrict__ bias, const float* __restrict__ bnw,
             const float* __restrict__ bnb, const float* __restrict__ pos,
             int K, int mts, int Mrow)
{
    __shared__ us Ah[2][GBM * GBK];
    __shared__ us Al[2][GBM * GBK];
    __shared__ us Bh[2][GBN * GBK];
    __shared__ us Bl[2][GBN * GBK];   // 64 KB total -> 2 blocks/CU (16 waves)

    const int tid = threadIdx.x;
    // XCD-bijective remap (nwg % 8 == 0 for all launches), m-fastest for B-panel L2 reuse
    int nwg = gridDim.x;
    int wg = (blockIdx.x & 7) * (nwg >> 3) + (blockIdx.x >> 3);
    int mt = wg & ((1 << mts) - 1);
    int rt = wg >> mts;
    const int m0 = mt * GBM;
    const int r0 = rt * GBN;

    const us* Ahg = Wh + (size_t)m0 * K;
    const us* Alg = Wl + (size_t)m0 * K;
    const us* Bhg = Xh + (size_t)r0 * K;
    const us* Blg = Xl + (size_t)r0 * K;

    const int lane = tid & 63;
    const int w    = tid >> 6;            // 0..7
    const int wm   = (w >> 2) * 64;       // 2 m-groups
    const int wr   = (w & 3) * 32;        // 4 r-groups
    const int l15  = lane & 15;
    const int lg   = lane >> 4;
    const int s2k  = (l15 >> 1) & 3;
    const int koff = ((lg ^ s2k) & 3) << 3;      // swizzled 16B slot within 32-el row

    const int arow = tid >> 2;            // 0..127
    const int asub = (tid & 3) << 3;

    f32x4 acc[4][2];
    #pragma unroll
    for (int a = 0; a < 4; a++)
        #pragma unroll
        for (int b = 0; b < 2; b++)
            acc[a][b] = (f32x4){0.f, 0.f, 0.f, 0.f};

    const int nst = K >> 5;

    #define STAGE(buf, k0)                                                        \
    {                                                                             \
        gl16(Ahg + (size_t)arow * K + (k0) + asub, &Ah[buf][tid * 8]);            \
        gl16(Alg + (size_t)arow * K + (k0) + asub, &Al[buf][tid * 8]);            \
        gl16(Bhg + (size_t)arow * K + (k0) + asub, &Bh[buf][tid * 8]);            \
        gl16(Blg + (size_t)arow * K + (k0) + asub, &Bl[buf][tid * 8]);            \
    }

    STAGE(0, 0);
    __syncthreads();
    int cur = 0;
    for (int s = 0; s < nst; s++) {
        if (s + 1 < nst) STAGE(cur ^ 1, (s + 1) << 5);
        const us* AHc = &Ah[cur][0];
        const us* ALc = &Al[cur][0];
        const us* BHc = &Bh[cur][0];
        const us* BLc = &Bl[cur][0];
        s16x8 va[4], wa[4], vb[2], ub[2];
        #pragma unroll
        for (int a = 0; a < 4; a++) {
            int off = (wm + a * 16 + l15) * GBK + koff;
            va[a] = *(const s16x8*)(AHc + off);
            wa[a] = *(const s16x8*)(ALc + off);
        }
        #pragma unroll
        for (int b = 0; b < 2; b++) {
            int off = (wr + b * 16 + l15) * GBK + koff;
            vb[b] = *(const s16x8*)(BHc + off);
            ub[b] = *(const s16x8*)(BLc + off);
        }
        #pragma unroll
        for (int a = 0; a < 4; a++)
            #pragma unroll
            for (int b = 0; b < 2; b++) {
                acc[a][b] = __builtin_amdgcn_mfma_f32_16x16x32_bf16(va[a], vb[b], acc[a][b], 0, 0, 0);
                acc[a][b] = __builtin_amdgcn_mfma_f32_16x16x32_bf16(va[a], ub[b], acc[a][b], 0, 0, 0);
                acc[a][b] = __builtin_amdgcn_mfma_f32_16x16x32_bf16(wa[a], vb[b], acc[a][b], 0, 0, 0);
            }
        __syncthreads();
        cur ^= 1;
    }
    #undef STAGE

    // epilogue: D row=(lane>>4)*4+reg (m-dim), col=lane&15 (r-dim)
    if (EPI == GE_F32) {
        #pragma unroll
        for (int a = 0; a < 4; a++) {
            int mb = m0 + wm + a * 16 + lg * 4;
            #pragma unroll
            for (int b = 0; b < 2; b++) {
                int rr = r0 + wr + b * 16 + l15;
                #pragma unroll
                for (int q = 0; q < 4; q++)
                    Yf[(size_t)(mb + q) * R_ + rr] = acc[a][b][q] + bias[mb + q];
            }
        }
    } else {
        #pragma unroll
        for (int b = 0; b < 2; b++) {
            int rr = r0 + wr + b * 16 + l15;
            int s2r = (rr >> 1) & 3;
            int l = rr % L_;
            size_t rowo = (size_t)rr * Mrow;
            #pragma unroll
            for (int a = 0; a < 4; a++) {
                int mb = m0 + wm + a * 16 + lg * 4;
                us hh[4], ll[4];
                #pragma unroll
                for (int q = 0; q < 4; q++) {
                    int m = mb + q;
                    float v = acc[a][b][q] + bias[m];
                    if (EPI == GE_CONVT) {
                        v = v * 0.9999950000374997f * bnw[m] + bnb[m];
                        v += pos[(size_t)m * L_ + l];
                    } else {
                        v = 0.5f * v * (1.f + erff(v * 0.7071067811865475f));
                    }
                    split2(v, hh[q], ll[q]);
                }
                int p = swz2(mb >> 3, s2r);
                size_t off = rowo + (size_t)((p << 3) | (mb & 7));
                *(uint2*)(Yth + off) = packu2(hh);
                *(uint2*)(Ytl + off) = packu2(ll);
            }
        }
    }
}

// pos[c][l]: c<64: sin(y*om) | <128: cos(y*om) | <192: sin(x*om) | <256: cos(x*om)
__global__ __launch_bounds__(256)
void pos_k(float* __restrict__ pos)
{
    int c = blockIdx.x;
    int q = c >> 6, t = c & 63;
    float om = exp2f(-(float)t * (13.287712379549449f / 64.f));  // 10000^(-t/64)
    for (int l = threadIdx.x; l < L_; l += 256) {
        int y = l / 56, x = l - y * 56;
        float arg = (q < 2 ? (float)y : (float)x) * om;
        pos[(size_t)c * L_ + l] = (q & 1) ? cosf(arg) : sinf(arg);
    }
}

// avgpool2(a3) -> a3d (fp32 residual) and xq_t = bf16T(a3d + pos) (swizzled)
__global__ __launch_bounds__(256)
void pool_k(const float* __restrict__ a3, const float* __restrict__ pos,
            float* __restrict__ a3d, us* __restrict__ xh, us* __restrict__ xl)
{
    __shared__ us hi[256][34];
    __shared__ us lo[256][34];
    int blk = blockIdx.x;                 // 784 = 8b * 98 lblk
    int b = blk / 98, l0 = (blk % 98) * 32;
    int t = threadIdx.x;
    {
        int lt = t & 31, cg = t >> 5;
        int l = l0 + lt;
        int y = l / 56, x = l - y * 56;
        const float* srow = a3 + ((size_t)b * 256) * 12544 + (2 * y) * 112 + 2 * x;
        float* drow = a3d + (size_t)b * L_ + l;
        const float* prow = pos + l;
        for (int cc = 0; cc < 32; cc++) {
            int c = cc * 8 + cg;
            const float* sp = srow + (size_t)c * 12544;
            float2 v0 = *(const float2*)sp;
            float2 v1 = *(const float2*)(sp + 112);
            float v = (v0.x + v0.y + v1.x + v1.y) * 0.25f;
            drow[(size_t)c * R_] = v;
            split2(v + prow[(size_t)c * L_], hi[c][lt], lo[c][lt]);
        }
    }
    __syncthreads();
    int j = t & 31, cq = t >> 5;
    int r = b * L_ + l0 + j;
    int s2 = ((l0 + j) >> 1) & 3;
    size_t rowo = (size_t)r * 256;
    #pragma unroll
    for (int gg = 0; gg < 4; gg++) {
        int cb = cq * 32 + gg * 8;
        us hh[8], ll[8];
        #pragma unroll
        for (int e = 0; e < 8; e++) { hh[e] = hi[cb + e][j]; ll[e] = lo[cb + e][j]; }
        int p = swz2((cq << 2) | gg, s2);
        *(uint4*)(xh + rowo + (size_t)p * 8) = packu4(hh);
        *(uint4*)(xl + rowo + (size_t)p * 8) = packu4(ll);
    }
}

// In-place LayerNorm (eps 1e-5) over channel dim then l2-normalize (max(n,1e-4)).
// Values cached in registers: one global read pass instead of three.
__global__ __launch_bounds__(256)
void ln_l2_k(float* __restrict__ X, const float* __restrict__ wt, const float* __restrict__ bt)
{
    __shared__ float red[4][64];
    __shared__ float red2[4][64];
    int tid = threadIdx.x;
    int rr = tid & 63, og = tid >> 6;
    size_t r = (size_t)blockIdx.x * 64 + rr;
    float vv[64];
    float s1 = 0.f, s2 = 0.f;
    for (int j = 0; j < 64; j++) {
        float v = X[(size_t)(og * 64 + j) * R_ + r];
        vv[j] = v;
        s1 += v; s2 = fmaf(v, v, s2);
    }
    red[og][rr] = s1; red2[og][rr] = s2;
    __syncthreads();
    float mu  = (red[0][rr] + red[1][rr] + red[2][rr] + red[3][rr]) * (1.f / 256.f);
    float var = (red2[0][rr] + red2[1][rr] + red2[2][rr] + red2[3][rr]) * (1.f / 256.f) - mu * mu;
    float rstd = rsqrtf(var + 1e-5f);
    __syncthreads();                       // protect red before reuse
    float t2 = 0.f;
    for (int j = 0; j < 64; j++) {
        int o = og * 64 + j;
        float y = (vv[j] - mu) * rstd * wt[o] + bt[o];
        t2 = fmaf(y, y, t2);
    }
    red[og][rr] = t2;
    __syncthreads();
    float nrm = sqrtf(red[0][rr] + red[1][rr] + red[2][rr] + red[3][rr]);
    float scale = 1.f / fmaxf(nrm, 1e-4f);
    for (int j = 0; j < 64; j++) {
        int o = og * 64 + j;
        size_t ix = (size_t)o * R_ + r;
        X[ix] = (vv[j] - mu) * rstd * wt[o] * scale + bt[o] * scale;
    }
}

// In-place X = res + LayerNorm(X); optionally also bf16T swizzled copy for next GEMM
template<int TOUT>
__global__ __launch_bounds__(256)
void ln_res_k(float* __restrict__ X, const float* __restrict__ res,
              const float* __restrict__ wt, const float* __restrict__ bt,
              us* __restrict__ th, us* __restrict__ tl_)
{
    __shared__ float red[4][64];
    __shared__ float red2[4][64];
    int tid = threadIdx.x;
    int rr = tid & 63, og = tid >> 6;
    size_t r = (size_t)blockIdx.x * 64 + rr;
    float s1 = 0.f, s2 = 0.f;
    for (int j = 0; j < 64; j++) {
        float v = X[(size_t)(og * 64 + j) * R_ + r];
        s1 += v; s2 = fmaf(v, v, s2);
    }
    red[og][rr] = s1; red2[og][rr] = s2;
    __syncthreads();
    float mu  = (red[0][rr] + red[1][rr] + red[2][rr] + red[3][rr]) * (1.f / 256.f);
    float var = (red2[0][rr] + red2[1][rr] + red2[2][rr] + red2[3][rr]) * (1.f / 256.f) - mu * mu;
    float rstd = rsqrtf(var + 1e-5f);
    float yv[64];
    #pragma unroll
    for (int j = 0; j < 64; j++) {
        int o = og * 64 + j;
        size_t ix = (size_t)o * R_ + r;
        float v = X[ix];
        float y = res[ix] + (v - mu) * rstd * wt[o] + bt[o];
        X[ix] = y;
        yv[j] = y;
    }
    if (TOUT) {
        int s2r = ((int)r >> 1) & 3;
        size_t rowo = r * 256;
        #pragma unroll
        for (int g = 0; g < 8; g++) {
            us hh[8], ll[8];
            #pragma unroll
            for (int e = 0; e < 8; e++) split2(yv[g * 8 + e], hh[e], ll[e]);
            int p = swz2((og << 3) | g, s2r);
            *(uint4*)(th  + rowo + (size_t)p * 8) = packu4(hh);
            *(uint4*)(tl_ + rowo + (size_t)p * 8) = packu4(ll);
        }
    }
}

// Partial KV: kvp[n][slab][d][m] = sum_{l in slab} (d<32?cw:sw)[l]*K[l][d&31]*V[l][m]
__global__ __launch_bounds__(256)
void kv_part_k(const float* __restrict__ Kt, const float* __restrict__ Vt,
               float* __restrict__ kvp)
{
    __shared__ float kl[64][33];
    __shared__ float vl[64][33];
    __shared__ float cwl[64], swl[64];
    int slab = blockIdx.x;
    int n = blockIdx.y;
    int b = n >> 3, h = n & 7;
    int tid = threadIdx.x;
    int lane = tid & 63, grp = tid >> 6;
    int d = tid >> 2;
    int m0 = (tid & 3) * 8;
    float acc[8] = {0,0,0,0,0,0,0,0};
    size_t base = (size_t)(h * 32) * R_ + (size_t)b * L_;
    for (int ch = 0; ch < 7; ch++) {
        int l0 = slab * 448 + ch * 64;
        #pragma unroll
        for (int j = 0; j < 8; j++) {
            int dd = grp * 8 + j;
            kl[lane][dd] = Kt[base + (size_t)dd * R_ + l0 + lane];
            vl[lane][dd] = Vt[base + (size_t)dd * R_ + l0 + lane];
        }
        if (tid < 64) {
            float wi = (float)(l0 + tid + 1) * (1.f / 3136.f);
            cwl[tid] = cosf(wi); swl[tid] = sinf(wi);
        }
        __syncthreads();
        for (int l = 0; l < 64; l++) {
            float kvv = (d < 32 ? cwl[l] : swl[l]) * kl[l][d & 31];
            #pragma unroll
            for (int j = 0; j < 8; j++)
                acc[j] = fmaf(kvv, vl[l][m0 + j], acc[j]);
        }
        __syncthreads();
    }
    float* out = kvp + ((size_t)(n * 7 + slab)) * 2048 + d * 32 + m0;
    #pragma unroll
    for (int j = 0; j < 8; j++) out[j] = acc[j];
}

__global__ __launch_bounds__(256)
void kv_red_k(const float* __restrict__ kvp, float* __restrict__ kv)
{
    int idx = blockIdx.x * 256 + threadIdx.x;
    int n = idx >> 11, dm = idx & 2047;
    float s = 0.f;
    #pragma unroll
    for (int t = 0; t < 7; t++) s += kvp[((size_t)(n * 7 + t)) * 2048 + dm];
    kv[idx] = s;
}

// attn -> rmsnorm -> bf16T swizzled output [r][c=h*32+m]
__global__ __launch_bounds__(256)
void attn_k(const float* __restrict__ Q, const float* __restrict__ kv,
            const float* __restrict__ rmsw, us* __restrict__ Gh, us* __restrict__ Gl)
{
    __shared__ float kvl[2048];
    int h = blockIdx.y, b = blockIdx.z;
    int tid = threadIdx.x;
    int n = b * 8 + h;
    for (int i = tid; i < 2048; i += 256) kvl[i] = kv[(size_t)n * 2048 + i];
    __syncthreads();
    int l = blockIdx.x * 256 + tid;
    if (l >= L_) return;
    size_t r = (size_t)b * L_ + l;
    float qd[32];
    #pragma unroll
    for (int dd = 0; dd < 32; dd++) qd[dd] = Q[((size_t)(h * 32 + dd)) * R_ + r];
    float wi = (float)(l + 1) * (1.f / 3136.f);
    float cw = cosf(wi), sw = sinf(wi);
    float val[32]; float ss = 0.f;
    #pragma unroll
    for (int m = 0; m < 32; m++) {
        float s1 = 0.f, s2 = 0.f;
        #pragma unroll
        for (int dd = 0; dd < 32; dd++) {
            s1 = fmaf(qd[dd], kvl[dd * 32 + m], s1);
            s2 = fmaf(qd[dd], kvl[(dd + 32) * 32 + m], s2);
        }
        float v = cw * s1 + sw * s2;
        val[m] = v; ss = fmaf(v, v, ss);
    }
    float rinv = rsqrtf(ss * (1.f / 32.f) + 1e-6f);
    int s2w = (l >> 1) & 3;
    size_t rowo = r * 256;
    #pragma unroll
    for (int j = 0; j < 4; j++) {
        us hh[8], ll[8];
        #pragma unroll
        for (int e = 0; e < 8; e++) {
            float y = rmsw[j * 8 + e] * val[j * 8 + e] * rinv;
            split2(y, hh[e], ll[e]);
        }
        int p = swz2((h << 2) | j, s2w);
        *(uint4*)(Gh + rowo + (size_t)p * 8) = packu4(hh);
        *(uint4*)(Gl + rowo + (size_t)p * 8) = packu4(ll);
    }
}

// ---------- 2x upsample (align_corners=False): one thread -> 2x2 output quad ----------
// xo=2k: 0.25*v[k-1]+0.75*v[k];  xo=2k+1: 0.75*v[k]+0.25*v[k+1]  (clamped)
__global__ __launch_bounds__(256)
void up_a3_k(const float* __restrict__ out2, const float* __restrict__ a3,
             float* __restrict__ out)
{
    unsigned idx = blockIdx.x * 256u + threadIdx.x;   // < 6422528
    int k = idx % 56;
    unsigned t1 = idx / 56;
    int j = t1 % 56;
    unsigned t2 = t1 / 56;
    int c = t2 & 255;
    int b = t2 >> 8;
    int km = k > 0 ? k - 1 : 0, kp = k < 55 ? k + 1 : 55;
    int jm = j > 0 ? j - 1 : 0, jp = j < 55 ? j + 1 : 55;
    const float* src = out2 + (size_t)c * R_ + (size_t)b * L_;
    const float* r0 = src + jm * 56;
    const float* r1 = src + j  * 56;
    const float* r2 = src + jp * 56;
    float h00 = fmaf(0.25f, r0[km], 0.75f * r0[k]);
    float h01 = fmaf(0.25f, r0[kp], 0.75f * r0[k]);
    float h10 = fmaf(0.25f, r1[km], 0.75f * r1[k]);
    float h11 = fmaf(0.25f, r1[kp], 0.75f * r1[k]);
    float h20 = fmaf(0.25f, r2[km], 0.75f * r2[k]);
    float h21 = fmaf(0.25f, r2[kp], 0.75f * r2[k]);
    float o00 = fmaf(0.25f, h00, 0.75f * h10);
    float o01 = fmaf(0.25f, h01, 0.75f * h11);
    float o10 = fmaf(0.25f, h20, 0.75f * h10);
    float o11 = fmaf(0.25f, h21, 0.75f * h11);
    size_t obase = (((size_t)(b * 256 + c) * 112) + 2 * j) * 112 + 2 * k;
    const float* ap = a3 + obase;
    float2 a0 = *(const float2*)ap;
    float2 a1 = *(const float2*)(ap + 112);
    float2 w0 = {o00 * a0.x, o01 * a0.y};
    float2 w1 = {o10 * a1.x, o11 * a1.y};
    *(float2*)(out + obase) = w0;
    *(float2*)(out + obase + 112) = w1;
}

__global__ __launch_bounds__(256)
void up_a4_k(const float* __restrict__ a4, float* __restrict__ out)
{
    unsigned idx = blockIdx.x * 256u + threadIdx.x;   // < 12845056
    int k = idx % 56;
    unsigned t1 = idx / 56;
    int j = t1 % 56;
    unsigned t2 = t1 / 56;
    int c = t2 & 511;
    int b = t2 >> 9;
    int km = k > 0 ? k - 1 : 0, kp = k < 55 ? k + 1 : 55;
    int jm = j > 0 ? j - 1 : 0, jp = j < 55 ? j + 1 : 55;
    const float* src = a4 + (size_t)(b * 512 + c) * 3136;
    const float* r0 = src + jm * 56;
    const float* r1 = src + j  * 56;
    const float* r2 = src + jp * 56;
    float h00 = fmaf(0.25f, r0[km], 0.75f * r0[k]);
    float h01 = fmaf(0.25f, r0[kp], 0.75f * r0[k]);
    float h10 = fmaf(0.25f, r1[km], 0.75f * r1[k]);
    float h11 = fmaf(0.25f, r1[kp], 0.75f * r1[k]);
    float h20 = fmaf(0.25f, r2[km], 0.75f * r2[k]);
    float h21 = fmaf(0.25f, r2[kp], 0.75f * r2[k]);
    float o00 = fmaf(0.25f, h00, 0.75f * h10);
    float o01 = fmaf(0.25f, h01, 0.75f * h11);
    float o10 = fmaf(0.25f, h20, 0.75f * h10);
    float o11 = fmaf(0.25f, h21, 0.75f * h11);
    size_t obase = (((size_t)(b * 512 + c) * 112) + 2 * j) * 112 + 2 * k;
    *(float2*)(out + obase) = (float2){o00, o01};
    *(float2*)(out + obase + 112) = (float2){o10, o11};
}

extern "C" void kernel_launch(void* const* d_in, const int* in_sizes, int n_in,
                              void* d_out, int out_size, void* d_ws, size_t ws_size,
                              hipStream_t stream)
{
    const float* a3     = (const float*)d_in[0];
    const float* a4     = (const float*)d_in[1];
    const float* conv_w = (const float*)d_in[2];
    const float* conv_b = (const float*)d_in[3];
    const float* bn_w   = (const float*)d_in[4];
    const float* bn_b   = (const float*)d_in[5];
    const float* q_w    = (const float*)d_in[6];
    const float* q_b    = (const float*)d_in[7];
    const float* q_ln_w = (const float*)d_in[8];
    const float* q_ln_b = (const float*)d_in[9];
    const float* k_w    = (const float*)d_in[10];
    const float* k_b    = (const float*)d_in[11];
    const float* k_ln_w = (const float*)d_in[12];
    const float* k_ln_b = (const float*)d_in[13];
    const float* v_w    = (const float*)d_in[14];
    const float* v_b    = (const float*)d_in[15];
    const float* o_w    = (const float*)d_in[16];
    const float* o_b    = (const float*)d_in[17];
    const float* rms_w  = (const float*)d_in[18];
    const float* l1_w   = (const float*)d_in[19];
    const float* l1_b   = (const float*)d_in[20];
    const float* l2_w   = (const float*)d_in[21];
    const float* l2_b   = (const float*)d_in[22];
    const float* n1_w   = (const float*)d_in[23];
    const float* n1_b   = (const float*)d_in[24];
    const float* n2_w   = (const float*)d_in[25];
    const float* n2_b   = (const float*)d_in[26];
    (void)in_sizes; (void)n_in; (void)out_size;

    // Arena (floats), same 53,231,616-float footprint:
    // pos | P0:a3d | P1:Cxt/Hot | P2:Ho | P3:Fv/out2 | P4:xqt/Gat/ffn0 |
    // P5:a4t_h/Dq/ffn1 | P6:a4t_l/Ek/ffn2 | P7:ffn3 | kvp(+convW) | kvb
    float* ws  = (float*)d_ws;
    float* pos = ws;
    float* P0  = ws + 802816;
    float* P1  = P0 + MATF;
    float* P2  = P1 + MATF;
    float* P3  = P2 + MATF;
    float* P4  = P3 + MATF;
    float* P5  = P4 + MATF;
    float* P6  = P5 + MATF;
    float* P7  = P6 + MATF;
    float* kvp = P7 + MATF;
    float* kvb = kvp + 917504;
    if (ws_size < (size_t)53231616 * 4) return;

    us* xqt_h = (us*)P4;  us* xqt_l = xqt_h + MATF;
    us* a4t_h = (us*)P5;  us* a4t_l = (us*)P6;
    us* Cxt_h = (us*)P1;  us* Cxt_l = Cxt_h + MATF;
    us* Gat_h = (us*)P4;  us* Gat_l = Gat_h + MATF;
    us* Hot_h = (us*)P1;  us* Hot_l = Hot_h + MATF;
    us* ffn_h = (us*)P4;  us* ffn_l = (us*)P6;     // each spans 2 regions (25088x1024)
    float* Dq = P5;
    float* Ek = P6;
    float* Fv = P3;
    float* Ho = P2;
    us* wb   = (us*)pos;                           // q,k,v,o,l1,l2 hi/lo after conv-gemm
    us* wc_h = (us*)kvp;  us* wc_l = wc_h + 131072;

    pos_k  <<<256, 256, 0, stream>>>(pos);
    wconv1_k<<<64, 256, 0, stream>>>(conv_w, wc_h, wc_l);
    tconv_k<<<dim3(49, 8, 8), 256, 0, stream>>>(a4, a4t_h, a4t_l, 512, 3136);
    pool_k <<<784, 256, 0, stream>>>(a3, pos, P0, xqt_h, xqt_l);
    gemm_mf<GE_CONVT><<<392, 512, 0, stream>>>(wc_h, wc_l, a4t_h, a4t_l,
        nullptr, Cxt_h, Cxt_l, conv_b, bn_w, bn_b, pos, 512, 1, 256);
    wconv6_k<<<384, 256, 0, stream>>>(q_w, k_w, v_w, o_w, l1_w, l2_w, wb);
    gemm_mf<GE_F32><<<392, 512, 0, stream>>>(wb, wb + 65536, xqt_h, xqt_l,
        Dq, nullptr, nullptr, q_b, nullptr, nullptr, nullptr, 256, 1, 256);
    ln_l2_k<<<392, 256, 0, stream>>>(Dq, q_ln_w, q_ln_b);
    gemm_mf<GE_F32><<<392, 512, 0, stream>>>(wb + 131072, wb + 196608, Cxt_h, Cxt_l,
        Ek, nullptr, nullptr, k_b, nullptr, nullptr, nullptr, 256, 1, 256);
    ln_l2_k<<<392, 256, 0, stream>>>(Ek, k_ln_w, k_ln_b);
    gemm_mf<GE_F32><<<392, 512, 0, stream>>>(wb + 262144, wb + 327680, Cxt_h, Cxt_l,
        Fv, nullptr, nullptr, v_b, nullptr, nullptr, nullptr, 256, 1, 256);
    kv_part_k<<<dim3(7, 64), 256, 0, stream>>>(Ek, Fv, kvp);
    kv_red_k<<<512, 256, 0, stream>>>(kvp, kvb);
    attn_k<<<dim3(13, 8, 8), 256, 0, stream>>>(Dq, kvb, rms_w, Gat_h, Gat_l);
    gemm_mf<GE_F32><<<392, 512, 0, stream>>>(wb + 393216, wb + 458752, Gat_h, Gat_l,
        Ho, nullptr, nullptr, o_b, nullptr, nullptr, nullptr, 256, 1, 256);
    ln_res_k<1><<<392, 256, 0, stream>>>(Ho, P0, n1_w, n1_b, Hot_h, Hot_l);
    gemm_mf<GE_GELUT><<<1568, 512, 0, stream>>>(wb + 524288, wb + 786432, Hot_h, Hot_l,
        nullptr, ffn_h, ffn_l, l1_b, nullptr, nullptr, nullptr, 256, 3, 1024);
    gemm_mf<GE_F32><<<392, 512, 0, stream>>>(wb + 1048576, wb + 1310720, ffn_h, ffn_l,
        Fv, nullptr, nullptr, l2_b, nullptr, nullptr, nullptr, 1024, 1, 256);
    ln_res_k<0><<<392, 256, 0, stream>>>(Fv, Ho, n2_w, n2_b, nullptr, nullptr);
    up_a3_k<<<25088, 256, 0, stream>>>(Fv, a3, (float*)d_out);
    up_a4_k<<<50176, 256, 0, stream>>>(a4, (float*)d_out + 25690112);
}